// Round 2
// baseline (678.977 us; speedup 1.0000x reference)
//
#include <hip/hip_runtime.h>

#define SEQ 2048
#define NB 4
#define DIN 768
#define EDIM 768
#define NH 12
#define QKVN 2304
#define SCALE 0.125f
#define PADV -1e9f
#define INV12 (0.0833333333f)
#define PSW 520   // Ps row stride in elems

typedef unsigned short ushort_t;
typedef __attribute__((ext_vector_type(8))) short bf16x8;
typedef __attribute__((ext_vector_type(4))) float f32x4;

__device__ __forceinline__ float bf2f(ushort_t u) {
    union { unsigned int i; float f; } v; v.i = ((unsigned int)u) << 16; return v.f;
}
__device__ __forceinline__ ushort_t f2bf(float f) {
    union { float f; unsigned int i; } v; v.f = f;
    unsigned int r = (v.i + 0x7fffu + ((v.i >> 16) & 1u)) >> 16;
    return (ushort_t)r;
}
__device__ __forceinline__ void gl_lds16(const ushort_t* g, ushort_t* l) {
    __builtin_amdgcn_global_load_lds(
        (const __attribute__((address_space(1))) unsigned int*)(g),
        (__attribute__((address_space(3))) unsigned int*)(l),
        16, 0, 0);
}

// ---------------- fp32 -> bf16 conversion, 3 regions in one launch ----------------
__global__ void cvt3_kernel(const float* __restrict__ s0, int n0,
                            const float* __restrict__ s1, int n1,
                            const float* __restrict__ s2, int n2,
                            ushort_t* __restrict__ d0, ushort_t* __restrict__ d1,
                            ushort_t* __restrict__ d2) {
    int i = blockIdx.x * blockDim.x + threadIdx.x;
    const float* src; ushort_t* dst; int off;
    if (i < n0)               { src = s0; dst = d0; off = i; }
    else if (i < n0 + n1)     { src = s1; dst = d1; off = i - n0; }
    else if (i < n0 + n1 + n2){ src = s2; dst = d2; off = i - n0 - n1; }
    else return;
    float4 f = ((const float4*)src)[off];
    ushort4 u;
    u.x = f2bf(f.x); u.y = f2bf(f.y); u.z = f2bf(f.z); u.w = f2bf(f.w);
    ((ushort4*)dst)[off] = u;
}

// ---------------- 128x128 bf16 MFMA GEMM ----------------
// MODE 0: fp32 out. MODE 1: bf16 out split into qkh[b][h][tok][128] (Q|K) and
// vt[b][h][d][tok] (transposed V).
template<int MODE>
__global__ __launch_bounds__(256) void mfma_gemm128(
    const ushort_t* __restrict__ A, const ushort_t* __restrict__ Bw,
    const float* __restrict__ bias, float* __restrict__ outf,
    ushort_t* __restrict__ qkh, ushort_t* __restrict__ vt, int N, int K)
{
    __shared__ __align__(16) ushort_t Al[128 * 64];
    __shared__ __align__(16) ushort_t Bl[128 * 64];
    const int tid  = threadIdx.x;
    const int w    = tid >> 6;
    const int l    = tid & 63;
    const int quad = l >> 4;
    const int lr   = l & 15;
    const int mw   = (w >> 1) * 64;
    const int nw   = (w & 1) * 64;
    const int bm   = blockIdx.y * 128;
    const int bn   = blockIdx.x * 128;
    const int srow = l >> 3;
    const int sg   = (l & 7) ^ srow;

    f32x4 acc[4][4];
    #pragma unroll
    for (int i = 0; i < 4; ++i)
        #pragma unroll
        for (int j = 0; j < 4; ++j)
            #pragma unroll
            for (int r = 0; r < 4; ++r) acc[i][j][r] = 0.f;

    const ushort_t* ga = A  + (size_t)(bm + w * 32 + srow) * K + sg * 8;
    const ushort_t* gb = Bw + (size_t)(bn + w * 32 + srow) * K + sg * 8;
    ushort_t* la = &Al[(w * 32) * 64];
    ushort_t* lb = &Bl[(w * 32) * 64];

    for (int k0 = 0; k0 < K; k0 += 64) {
        __syncthreads();
        #pragma unroll
        for (int i = 0; i < 4; ++i)
            gl_lds16(ga + (size_t)(i * 8) * K + k0, la + i * 8 * 64);
        #pragma unroll
        for (int i = 0; i < 4; ++i)
            gl_lds16(gb + (size_t)(i * 8) * K + k0, lb + i * 8 * 64);
        __syncthreads();
        #pragma unroll
        for (int s = 0; s < 2; ++s) {
            bf16x8 af[4], bf[4];
            #pragma unroll
            for (int t = 0; t < 4; ++t)
                af[t] = *(const bf16x8*)&Al[(mw + t * 16 + lr) * 64 + (((4 * s + quad) ^ (lr & 7)) * 8)];
            #pragma unroll
            for (int t = 0; t < 4; ++t)
                bf[t] = *(const bf16x8*)&Bl[(nw + t * 16 + lr) * 64 + (((4 * s + quad) ^ (lr & 7)) * 8)];
            #pragma unroll
            for (int mt = 0; mt < 4; ++mt)
                #pragma unroll
                for (int nt = 0; nt < 4; ++nt)
                    acc[mt][nt] = __builtin_amdgcn_mfma_f32_16x16x32_bf16(af[mt], bf[nt], acc[mt][nt], 0, 0, 0);
        }
    }

    #pragma unroll
    for (int nt = 0; nt < 4; ++nt) {
        const int gn = bn + nw + nt * 16 + lr;
        const float bv = bias[gn];
        const int hh  = gn / 192;
        const int rem = gn - hh * 192;
        #pragma unroll
        for (int mt = 0; mt < 4; ++mt) {
            const int gm0 = bm + mw + mt * 16 + quad * 4;
            if (MODE == 0) {
                #pragma unroll
                for (int r = 0; r < 4; ++r)
                    outf[(size_t)(gm0 + r) * N + gn] = acc[mt][nt][r] + bv;
            } else if (rem < 128) {
                const int bb  = gm0 >> 11;
                const int tok = gm0 & (SEQ - 1);
                #pragma unroll
                for (int r = 0; r < 4; ++r)
                    qkh[((size_t)(bb * NH + hh) * SEQ + tok + r) * 128 + rem] =
                        f2bf(acc[mt][nt][r] + bv);
            } else {
                const int bb  = gm0 >> 11;
                const int tok = gm0 & (SEQ - 1);
                ushort4 st;
                st.x = f2bf(acc[mt][nt][0] + bv);
                st.y = f2bf(acc[mt][nt][1] + bv);
                st.z = f2bf(acc[mt][nt][2] + bv);
                st.w = f2bf(acc[mt][nt][3] + bv);
                *(ushort4*)&vt[((size_t)(bb * NH + hh) * 64 + (rem - 128)) * SEQ + tok] = st;
            }
        }
    }
}

// ---------------- fused windowed attention (round-0 inner structure) ----------------
// Round-2: head-split. Grid 1024, 512 thr = 8 waves. Each block owns a 16-row
// tile AND a head-half (6 heads = 3 pairs). attn_mean partials combined via
// fp32 atomicAdd into pre-zeroed attn_out (exactly 2 contributions/elem ->
// commutative -> deterministic). 4 blocks/CU (was 2): doubles latency hiding.
// Round-1 post-mortem: removing the trailing barrier desynced waves -> L2
// locality collapsed (FETCH 29->102 MB) -> slower. Barriers stay.
__global__ __launch_bounds__(512) void attn_kernel(
    const ushort_t* __restrict__ qkh,   // [NB*NH*SEQ][128] bf16 (Q|K per head)
    const ushort_t* __restrict__ vt,    // [NB*NH*64][SEQ] bf16 (V transposed)
    const float* __restrict__ mmask,    // [NB][SEQ][SEQ]
    const int* __restrict__ pad,        // [NB][SEQ]
    ushort_t* __restrict__ values,      // [NB*SEQ][768] bf16
    float* __restrict__ attn_out)       // [NB][SEQ][SEQ] (pre-zeroed)
{
    __shared__ __align__(16) ushort_t Ps[2][16 * PSW];  // 33.3 KB
    __shared__ float lsump[2][4][16];
    __shared__ int s_cnt[8];
    __shared__ int s_flags[8];
    const int tid  = threadIdx.x;
    const int w    = tid >> 6;       // 0..7
    const int hg   = w >> 2;         // head-group 0/1
    const int ww   = w & 3;          // wave within head
    const int lane = tid & 63;
    const int quad = lane >> 4;
    const int lr   = lane & 15;

    const int lin  = blockIdx.x;
    const int s    = lin & 1;
    const int b    = (lin >> 1) & 3;
    const int half = (lin >> 3) & 1;         // head-half: 0 -> h 0..5, 1 -> h 6..11
    const int i16  = (lin >> 4) + 64 * s;
    const int iq0  = i16 * 16;

    // ---- inline window size (popcount of valid tokens) ----
    {
        int4 pv = *(const int4*)&pad[b * SEQ + tid * 4];
        int c = (pv.x == 0) + (pv.y == 0) + (pv.z == 0) + (pv.w == 0);
        #pragma unroll
        for (int o = 32; o; o >>= 1) c += __shfl_down(c, o, 64);
        if (lane == 0) s_cnt[w] = c;
        if (tid < 8) s_flags[tid] = 0;
    }
    __syncthreads();
    int len = 0;
    #pragma unroll
    for (int k = 0; k < 8; ++k) len += s_cnt[k];
    if (len > 2048) len = 2048;
    int wsz = (int)ceilf((float)len * 10.0f / 100.0f);
    if (wsz < 2) wsz = 2;

    const int jlo  = max(0, iq0 - wsz);
    const int jhi  = min(SEQ - 1, iq0 + 15 + wsz);
    const int jt0  = jlo >> 6;
    const int nch  = (jhi >> 6) - jt0 + 1;   // <= 8
    const int jbase = jt0 << 6;
    const int span  = nch << 6;              // <= 512

    // ---- inline mmask nonzero-tile flags (coalesced scan of own window) ----
    {
        const float* tp = mmask + ((size_t)b * SEQ + iq0) * SEQ + jbase;
        const int e = tid * 2, row = e >> 6, col = e & 63;
        for (int ci = 0; ci < nch; ++ci) {
            float2 v = *(const float2*)&tp[(size_t)row * SEQ + ci * 64 + col];
            if (__any(v.x != 0.f || v.y != 0.f)) {
                if (lane == 0) atomicOr(&s_flags[ci], 1);
            }
        }
    }

    // mean-accum ownership: row = tid&15, col-group = tid>>4 (16 cols each)
    const int arow = tid & 15;
    const int acg  = tid >> 4;
    float acc[16];
    #pragma unroll
    for (int k = 0; k < 16; ++k) acc[k] = 0.f;
    __syncthreads();   // s_flags ready

    const ushort_t* vhead = vt + (size_t)b * NH * 64 * SEQ;

    for (int hp = 0; hp < 3; ++hp) {
        const int h = half * 6 + hp * 2 + hg;
        const ushort_t* hbase = qkh + (size_t)(b * NH + h) * SEQ * 128;
        const ushort_t* qbase = hbase + (size_t)(iq0 + lr) * 128;
        const bf16x8 qf0 = *(const bf16x8*)(qbase + quad * 8);
        const bf16x8 qf1 = *(const bf16x8*)(qbase + 32 + quad * 8);

        // ---- QK + exp for this wave's chunks (ci = ww, ww+4) ----
        float ls[4] = {0.f, 0.f, 0.f, 0.f};
        #pragma unroll
        for (int cc = 0; cc < 2; ++cc) {
            const int ci = ww + cc * 4;
            if (ci < nch) {
                const int jc = jbase + ci * 64;
                f32x4 s4[4];
                #pragma unroll
                for (int t = 0; t < 4; ++t) {
                    const ushort_t* kr = hbase + (size_t)(jc + t * 16 + lr) * 128 + 64;
                    bf16x8 kf0 = *(const bf16x8*)(kr + quad * 8);
                    bf16x8 kf1 = *(const bf16x8*)(kr + 32 + quad * 8);
                    #pragma unroll
                    for (int r = 0; r < 4; ++r) s4[t][r] = 0.f;
                    s4[t] = __builtin_amdgcn_mfma_f32_16x16x32_bf16(qf0, kf0, s4[t], 0, 0, 0);
                    s4[t] = __builtin_amdgcn_mfma_f32_16x16x32_bf16(qf1, kf1, s4[t], 0, 0, 0);
                }
                const int anym = s_flags[ci];
                #pragma unroll
                for (int t = 0; t < 4; ++t) {
                    const int gj = jc + t * 16 + lr;
                    #pragma unroll
                    for (int r = 0; r < 4; ++r) {
                        const int gi = iq0 + quad * 4 + r;
                        float mm = 0.f;
                        if (anym) mm = mmask[((size_t)b * SEQ + gi) * SEQ + gj];
                        const int dist = gi > gj ? gi - gj : gj - gi;
                        const float p = (dist > wsz) ? 0.f : __expf(fmaf(s4[t][r], SCALE, mm));
                        ls[r] += p;
                        Ps[hg][(quad * 4 + r) * PSW + (ci * 64 + t * 16 + lr)] = f2bf(p);
                    }
                }
            }
        }
        #pragma unroll
        for (int r = 0; r < 4; ++r) {
            #pragma unroll
            for (int m = 8; m; m >>= 1) ls[r] += __shfl_xor(ls[r], m, 16);
        }
        if (lr == 0) {
            #pragma unroll
            for (int r = 0; r < 4; ++r) lsump[hg][ww][quad * 4 + r] = ls[r];
        }
        __syncthreads();

        // ---- head-mean accumulation into registers (both heads of the pair) ----
        if (acg * 16 < span) {
            const float l0 = lsump[0][0][arow] + lsump[0][1][arow] + lsump[0][2][arow] + lsump[0][3][arow];
            const float l1 = lsump[1][0][arow] + lsump[1][1][arow] + lsump[1][2][arow] + lsump[1][3][arow];
            const float sc0 = INV12 / l0;
            const float sc1 = INV12 / l1;
            const ushort_t* p0 = &Ps[0][arow * PSW + acg * 16];
            const ushort_t* p1 = &Ps[1][arow * PSW + acg * 16];
            #pragma unroll
            for (int k = 0; k < 4; ++k) {
                ushort4 u0 = *(const ushort4*)(p0 + k * 4);
                ushort4 u1 = *(const ushort4*)(p1 + k * 4);
                acc[k * 4 + 0] = fmaf(bf2f(u0.x), sc0, fmaf(bf2f(u1.x), sc1, acc[k * 4 + 0]));
                acc[k * 4 + 1] = fmaf(bf2f(u0.y), sc0, fmaf(bf2f(u1.y), sc1, acc[k * 4 + 1]));
                acc[k * 4 + 2] = fmaf(bf2f(u0.z), sc0, fmaf(bf2f(u1.z), sc1, acc[k * 4 + 2]));
                acc[k * 4 + 3] = fmaf(bf2f(u0.w), sc0, fmaf(bf2f(u1.w), sc1, acc[k * 4 + 3]));
            }
        }

        // ---- PV: wave computes head h, d-slice [ww*16, ww*16+16) ----
        {
            f32x4 oacc;
            #pragma unroll
            for (int r = 0; r < 4; ++r) oacc[r] = 0.f;
            const ushort_t* vrow = vhead + (size_t)(h * 64 + ww * 16 + lr) * SEQ + jbase;
            for (int ci = 0; ci < nch; ++ci) {
                const int tok0 = ci * 64;
                #pragma unroll
                for (int s2 = 0; s2 < 2; ++s2) {
                    bf16x8 pa = *(const bf16x8*)&Ps[hg][lr * PSW + tok0 + s2 * 32 + quad * 8];
                    bf16x8 vf = *(const bf16x8*)(vrow + tok0 + s2 * 32 + quad * 8);
                    oacc = __builtin_amdgcn_mfma_f32_16x16x32_bf16(pa, vf, oacc, 0, 0, 0);
                }
            }
            float lr4[4];
            #pragma unroll
            for (int r = 0; r < 4; ++r)
                lr4[r] = lsump[hg][0][quad * 4 + r] + lsump[hg][1][quad * 4 + r] +
                         lsump[hg][2][quad * 4 + r] + lsump[hg][3][quad * 4 + r];
            #pragma unroll
            for (int r = 0; r < 4; ++r) {
                const int row = iq0 + quad * 4 + r;
                values[(size_t)(b * SEQ + row) * EDIM + h * 64 + ww * 16 + lr] =
                    f2bf(oacc[r] / lr4[r]);
            }
        }
        __syncthreads();   // Ps/lsump reuse next head pair (keeps waves time-aligned)
    }

    // ---- combine attn_mean partial via fp32 atomics (2 contributions/elem) ----
    if (acg * 16 < span) {
        float* dst = attn_out + ((size_t)b * SEQ + iq0 + arow) * SEQ + jbase + acg * 16;
        #pragma unroll
        for (int k = 0; k < 16; ++k)
            unsafeAtomicAdd(dst + k, acc[k]);
    }
    // out-of-window region: left at zero by the pre-pass memset
}

extern "C" void kernel_launch(void* const* d_in, const int* in_sizes, int n_in,
                              void* d_out, int out_size, void* d_ws, size_t ws_size,
                              hipStream_t stream) {
    const float* x      = (const float*)d_in[0];
    const int*   pad    = (const int*)d_in[1];
    const float* mmask  = (const float*)d_in[2];
    const float* qkv_w  = (const float*)d_in[3];
    const float* qkv_b  = (const float*)d_in[4];
    const float* o_w    = (const float*)d_in[5];
    const float* o_b    = (const float*)d_in[6];

    float* out_o    = (float*)d_out;
    float* out_attn = out_o + (size_t)NB * SEQ * EDIM;

    ushort_t* qkh    = (ushort_t*)d_ws;                       // NB*NH*SEQ*128  25.2 MB
    ushort_t* vt     = qkh + (size_t)NB * NH * SEQ * 128;     // NB*NH*64*SEQ   12.6 MB
    ushort_t* xb     = vt + (size_t)NB * NH * 64 * SEQ;       // x bf16         12.6 MB
    ushort_t* values = xb;                                    // alias (after GEMM1)
    ushort_t* wqkvb  = xb + (size_t)NB * SEQ * DIN;           // qkv_w bf16      3.5 MB
    ushort_t* wob    = wqkvb + (size_t)QKVN * DIN;            // o_w bf16        1.2 MB

    // zero attn output early; attn kernel atomically accumulates the window region
    hipMemsetAsync(out_attn, 0, (size_t)NB * SEQ * SEQ * sizeof(float), stream);

    const int nx = NB * SEQ * DIN / 4, nw1 = QKVN * DIN / 4, nw2 = EDIM * EDIM / 4;
    cvt3_kernel<<<(nx + nw1 + nw2 + 255) / 256, 256, 0, stream>>>(
        x, nx, qkv_w, nw1, o_w, nw2, xb, wqkvb, wob);

    mfma_gemm128<1><<<dim3(QKVN / 128, (NB * SEQ) / 128), 256, 0, stream>>>(
        xb, wqkvb, qkv_b, nullptr, qkh, vt, QKVN, DIN);

    attn_kernel<<<1024, 512, 0, stream>>>(
        qkh, vt, mmask, pad, values, out_attn);

    mfma_gemm128<0><<<dim3(EDIM / 128, (NB * SEQ) / 128), 256, 0, stream>>>(
        values, wob, o_b, out_o, nullptr, nullptr, EDIM, EDIM);
}

// Round 4
// 423.116 us; speedup vs baseline: 1.6047x; 1.6047x over previous
//
#include <hip/hip_runtime.h>

#define SEQ 2048
#define NB 4
#define DIN 768
#define EDIM 768
#define NH 12
#define QKVN 2304
#define SCALE 0.125f
#define PADV -1e9f
#define INV12 (0.0833333333f)
#define PSW 520   // Ps row stride in elems

typedef unsigned short ushort_t;
typedef __attribute__((ext_vector_type(8))) short bf16x8;
typedef __attribute__((ext_vector_type(4))) float f32x4;

__device__ __forceinline__ float bf2f(ushort_t u) {
    union { unsigned int i; float f; } v; v.i = ((unsigned int)u) << 16; return v.f;
}
__device__ __forceinline__ ushort_t f2bf(float f) {
    union { float f; unsigned int i; } v; v.f = f;
    unsigned int r = (v.i + 0x7fffu + ((v.i >> 16) & 1u)) >> 16;
    return (ushort_t)r;
}
__device__ __forceinline__ void gl_lds16(const ushort_t* g, ushort_t* l) {
    __builtin_amdgcn_global_load_lds(
        (const __attribute__((address_space(1))) unsigned int*)(g),
        (__attribute__((address_space(3))) unsigned int*)(l),
        16, 0, 0);
}

// ---------------- fp32 -> bf16 conversion, 3 regions in one launch ----------------
__global__ void cvt3_kernel(const float* __restrict__ s0, int n0,
                            const float* __restrict__ s1, int n1,
                            const float* __restrict__ s2, int n2,
                            ushort_t* __restrict__ d0, ushort_t* __restrict__ d1,
                            ushort_t* __restrict__ d2) {
    int i = blockIdx.x * blockDim.x + threadIdx.x;
    const float* src; ushort_t* dst; int off;
    if (i < n0)               { src = s0; dst = d0; off = i; }
    else if (i < n0 + n1)     { src = s1; dst = d1; off = i - n0; }
    else if (i < n0 + n1 + n2){ src = s2; dst = d2; off = i - n0 - n1; }
    else return;
    float4 f = ((const float4*)src)[off];
    ushort4 u;
    u.x = f2bf(f.x); u.y = f2bf(f.y); u.z = f2bf(f.z); u.w = f2bf(f.w);
    ((ushort4*)dst)[off] = u;
}

// ---------------- 128x128 bf16 MFMA GEMM ----------------
// MODE 0: fp32 out. MODE 1: bf16 out split into qkh[b][h][tok][128] (Q|K) and
// vt[b][h][d][tok] (transposed V).
template<int MODE>
__global__ __launch_bounds__(256) void mfma_gemm128(
    const ushort_t* __restrict__ A, const ushort_t* __restrict__ Bw,
    const float* __restrict__ bias, float* __restrict__ outf,
    ushort_t* __restrict__ qkh, ushort_t* __restrict__ vt, int N, int K)
{
    __shared__ __align__(16) ushort_t Al[128 * 64];
    __shared__ __align__(16) ushort_t Bl[128 * 64];
    const int tid  = threadIdx.x;
    const int w    = tid >> 6;
    const int l    = tid & 63;
    const int quad = l >> 4;
    const int lr   = l & 15;
    const int mw   = (w >> 1) * 64;
    const int nw   = (w & 1) * 64;
    const int bm   = blockIdx.y * 128;
    const int bn   = blockIdx.x * 128;
    const int srow = l >> 3;
    const int sg   = (l & 7) ^ srow;

    f32x4 acc[4][4];
    #pragma unroll
    for (int i = 0; i < 4; ++i)
        #pragma unroll
        for (int j = 0; j < 4; ++j)
            #pragma unroll
            for (int r = 0; r < 4; ++r) acc[i][j][r] = 0.f;

    const ushort_t* ga = A  + (size_t)(bm + w * 32 + srow) * K + sg * 8;
    const ushort_t* gb = Bw + (size_t)(bn + w * 32 + srow) * K + sg * 8;
    ushort_t* la = &Al[(w * 32) * 64];
    ushort_t* lb = &Bl[(w * 32) * 64];

    for (int k0 = 0; k0 < K; k0 += 64) {
        __syncthreads();
        #pragma unroll
        for (int i = 0; i < 4; ++i)
            gl_lds16(ga + (size_t)(i * 8) * K + k0, la + i * 8 * 64);
        #pragma unroll
        for (int i = 0; i < 4; ++i)
            gl_lds16(gb + (size_t)(i * 8) * K + k0, lb + i * 8 * 64);
        __syncthreads();
        #pragma unroll
        for (int s = 0; s < 2; ++s) {
            bf16x8 af[4], bf[4];
            #pragma unroll
            for (int t = 0; t < 4; ++t)
                af[t] = *(const bf16x8*)&Al[(mw + t * 16 + lr) * 64 + (((4 * s + quad) ^ (lr & 7)) * 8)];
            #pragma unroll
            for (int t = 0; t < 4; ++t)
                bf[t] = *(const bf16x8*)&Bl[(nw + t * 16 + lr) * 64 + (((4 * s + quad) ^ (lr & 7)) * 8)];
            #pragma unroll
            for (int mt = 0; mt < 4; ++mt)
                #pragma unroll
                for (int nt = 0; nt < 4; ++nt)
                    acc[mt][nt] = __builtin_amdgcn_mfma_f32_16x16x32_bf16(af[mt], bf[nt], acc[mt][nt], 0, 0, 0);
        }
    }

    #pragma unroll
    for (int nt = 0; nt < 4; ++nt) {
        const int gn = bn + nw + nt * 16 + lr;
        const float bv = bias[gn];
        const int hh  = gn / 192;
        const int rem = gn - hh * 192;
        #pragma unroll
        for (int mt = 0; mt < 4; ++mt) {
            const int gm0 = bm + mw + mt * 16 + quad * 4;
            if (MODE == 0) {
                #pragma unroll
                for (int r = 0; r < 4; ++r)
                    outf[(size_t)(gm0 + r) * N + gn] = acc[mt][nt][r] + bv;
            } else if (rem < 128) {
                const int bb  = gm0 >> 11;
                const int tok = gm0 & (SEQ - 1);
                #pragma unroll
                for (int r = 0; r < 4; ++r)
                    qkh[((size_t)(bb * NH + hh) * SEQ + tok + r) * 128 + rem] =
                        f2bf(acc[mt][nt][r] + bv);
            } else {
                const int bb  = gm0 >> 11;
                const int tok = gm0 & (SEQ - 1);
                ushort4 st;
                st.x = f2bf(acc[mt][nt][0] + bv);
                st.y = f2bf(acc[mt][nt][1] + bv);
                st.z = f2bf(acc[mt][nt][2] + bv);
                st.w = f2bf(acc[mt][nt][3] + bv);
                *(ushort4*)&vt[((size_t)(bb * NH + hh) * 64 + (rem - 128)) * SEQ + tok] = st;
            }
        }
    }
}

// ---------------- fused windowed attention (round-0 structure + batched loads) ------
// Grid 512 (2 blocks/CU), 512 thr = 8 waves; waves 0-3 -> even head, 4-7 -> odd.
// Round-1 lesson: keep BOTH barriers (lockstep preserves L2 locality).
// Round-2 lesson: no global-atomic head split (write amplification).
// Round-3 lesson: no raw asm global loads (crashed).
// Round-4: branch-free load batches (OOB chunk indices CLAMPED to nch-1, results
// unused) + sched_barrier(0) after the batch so the scheduler cannot sink the
// loads to their uses. 18 K/Q loads in flight, then one compiler-placed wait;
// same for 16 V loads in PV. VGPR_Count rising past ~110 confirms the pin took.
__global__ __launch_bounds__(512, 4) void attn_kernel(
    const ushort_t* __restrict__ qkh,   // [NB*NH*SEQ][128] bf16 (Q|K per head)
    const ushort_t* __restrict__ vt,    // [NB*NH*64][SEQ] bf16 (V transposed)
    const float* __restrict__ mmask,    // [NB][SEQ][SEQ]
    const int* __restrict__ pad,        // [NB][SEQ]
    ushort_t* __restrict__ values,      // [NB*SEQ][768] bf16
    float* __restrict__ attn_out)       // [NB][SEQ][SEQ]
{
    __shared__ __align__(16) ushort_t Ps[2][16 * PSW];  // 33.3 KB
    __shared__ float lsump[2][4][16];
    __shared__ int s_cnt[8];
    __shared__ int s_flags[8];
    const int tid  = threadIdx.x;
    const int w    = tid >> 6;       // 0..7
    const int hg   = w >> 2;         // head-group 0/1
    const int ww   = w & 3;          // wave within head
    const int lane = tid & 63;
    const int quad = lane >> 4;
    const int lr   = lane & 15;

    const int lin  = blockIdx.x;
    const int s    = lin & 1;
    const int b    = (lin >> 1) & 3;
    const int i16  = (lin >> 3) + 64 * s;
    const int iq0  = i16 * 16;

    // ---- inline window size (popcount of valid tokens) ----
    {
        int4 pv = *(const int4*)&pad[b * SEQ + tid * 4];
        int c = (pv.x == 0) + (pv.y == 0) + (pv.z == 0) + (pv.w == 0);
        #pragma unroll
        for (int o = 32; o; o >>= 1) c += __shfl_down(c, o, 64);
        if (lane == 0) s_cnt[w] = c;
        if (tid < 8) s_flags[tid] = 0;
    }
    __syncthreads();
    int len = 0;
    #pragma unroll
    for (int k = 0; k < 8; ++k) len += s_cnt[k];
    if (len > 2048) len = 2048;
    int wsz = (int)ceilf((float)len * 10.0f / 100.0f);
    if (wsz < 2) wsz = 2;

    const int jlo  = max(0, iq0 - wsz);
    const int jhi  = min(SEQ - 1, iq0 + 15 + wsz);
    const int jt0  = jlo >> 6;
    const int nch  = (jhi >> 6) - jt0 + 1;   // <= 8
    const int jbase = jt0 << 6;
    const int span  = nch << 6;              // <= 512

    // ---- inline mmask nonzero-tile flags (coalesced scan of own window) ----
    {
        const float* tp = mmask + ((size_t)b * SEQ + iq0) * SEQ + jbase;
        const int e = tid * 2, row = e >> 6, col = e & 63;
        for (int ci = 0; ci < nch; ++ci) {
            float2 v = *(const float2*)&tp[(size_t)row * SEQ + ci * 64 + col];
            if (__any(v.x != 0.f || v.y != 0.f)) {
                if (lane == 0) atomicOr(&s_flags[ci], 1);
            }
        }
    }

    // mean-accum ownership: row = tid&15, col-group = tid>>4 (16 cols each)
    const int arow = tid & 15;
    const int acg  = tid >> 4;
    float acc[16];
    #pragma unroll
    for (int k = 0; k < 16; ++k) acc[k] = 0.f;
    __syncthreads();   // s_flags ready

    const ushort_t* vhead = vt + (size_t)b * NH * 64 * SEQ;

    for (int hp = 0; hp < NH / 2; ++hp) {
        const int h = hp * 2 + hg;
        const ushort_t* hbase = qkh + (size_t)(b * NH + h) * SEQ * 128;

        const int ci0 = ww;
        const int ci1 = ww + 4;
        const int c0  = ci0 < nch ? ci0 : nch - 1;   // clamped (valid rows, maybe unused)
        const int c1  = ci1 < nch ? ci1 : nch - 1;

        // ---- branch-free load batch: Q (2) + K chunk0 (8) + K chunk1 (8) ----
        const ushort_t* qbase = hbase + (size_t)(iq0 + lr) * 128 + quad * 8;
        const ushort_t* kr0 = hbase + (size_t)(jbase + c0 * 64 + lr) * 128 + 64 + quad * 8;
        const ushort_t* kr1 = hbase + (size_t)(jbase + c1 * 64 + lr) * 128 + 64 + quad * 8;
        bf16x8 qf0 = *(const bf16x8*)(qbase);
        bf16x8 qf1 = *(const bf16x8*)(qbase + 32);
        bf16x8 k0a[4], k0b[4], k1a[4], k1b[4];
        #pragma unroll
        for (int t = 0; t < 4; ++t) {
            k0a[t] = *(const bf16x8*)(kr0 + (size_t)t * 16 * 128);
            k0b[t] = *(const bf16x8*)(kr0 + (size_t)t * 16 * 128 + 32);
            k1a[t] = *(const bf16x8*)(kr1 + (size_t)t * 16 * 128);
            k1b[t] = *(const bf16x8*)(kr1 + (size_t)t * 16 * 128 + 32);
        }
        __builtin_amdgcn_sched_barrier(0);   // loads may not sink past this point

        // ---- MFMAs (18 round-trips amortized into one wait) ----
        f32x4 s40[4], s41[4];
        if (ci0 < nch) {
            #pragma unroll
            for (int t = 0; t < 4; ++t) {
                #pragma unroll
                for (int r = 0; r < 4; ++r) s40[t][r] = 0.f;
                s40[t] = __builtin_amdgcn_mfma_f32_16x16x32_bf16(qf0, k0a[t], s40[t], 0, 0, 0);
                s40[t] = __builtin_amdgcn_mfma_f32_16x16x32_bf16(qf1, k0b[t], s40[t], 0, 0, 0);
            }
        }
        if (ci1 < nch) {
            #pragma unroll
            for (int t = 0; t < 4; ++t) {
                #pragma unroll
                for (int r = 0; r < 4; ++r) s41[t][r] = 0.f;
                s41[t] = __builtin_amdgcn_mfma_f32_16x16x32_bf16(qf0, k1a[t], s41[t], 0, 0, 0);
                s41[t] = __builtin_amdgcn_mfma_f32_16x16x32_bf16(qf1, k1b[t], s41[t], 0, 0, 0);
            }
        }

        // ---- exp + Ps store + partial row-sums ----
        float ls[4] = {0.f, 0.f, 0.f, 0.f};
        if (ci0 < nch) {
            const int jc = jbase + ci0 * 64;
            const int anym = s_flags[ci0];
            #pragma unroll
            for (int t = 0; t < 4; ++t) {
                const int gj = jc + t * 16 + lr;
                #pragma unroll
                for (int r = 0; r < 4; ++r) {
                    const int gi = iq0 + quad * 4 + r;
                    float mm = 0.f;
                    if (anym) mm = mmask[((size_t)b * SEQ + gi) * SEQ + gj];
                    const int dist = gi > gj ? gi - gj : gj - gi;
                    const float p = (dist > wsz) ? 0.f : __expf(fmaf(s40[t][r], SCALE, mm));
                    ls[r] += p;
                    Ps[hg][(quad * 4 + r) * PSW + (ci0 * 64 + t * 16 + lr)] = f2bf(p);
                }
            }
        }
        if (ci1 < nch) {
            const int jc = jbase + ci1 * 64;
            const int anym = s_flags[ci1];
            #pragma unroll
            for (int t = 0; t < 4; ++t) {
                const int gj = jc + t * 16 + lr;
                #pragma unroll
                for (int r = 0; r < 4; ++r) {
                    const int gi = iq0 + quad * 4 + r;
                    float mm = 0.f;
                    if (anym) mm = mmask[((size_t)b * SEQ + gi) * SEQ + gj];
                    const int dist = gi > gj ? gi - gj : gj - gi;
                    const float p = (dist > wsz) ? 0.f : __expf(fmaf(s41[t][r], SCALE, mm));
                    ls[r] += p;
                    Ps[hg][(quad * 4 + r) * PSW + (ci1 * 64 + t * 16 + lr)] = f2bf(p);
                }
            }
        }
        #pragma unroll
        for (int r = 0; r < 4; ++r) {
            #pragma unroll
            for (int m = 8; m; m >>= 1) ls[r] += __shfl_xor(ls[r], m, 16);
        }
        if (lr == 0) {
            #pragma unroll
            for (int r = 0; r < 4; ++r) lsump[hg][ww][quad * 4 + r] = ls[r];
        }
        __syncthreads();

        // ---- head-mean accumulation into registers (both heads of the pair) ----
        if (acg * 16 < span) {
            const float l0 = lsump[0][0][arow] + lsump[0][1][arow] + lsump[0][2][arow] + lsump[0][3][arow];
            const float l1 = lsump[1][0][arow] + lsump[1][1][arow] + lsump[1][2][arow] + lsump[1][3][arow];
            const float sc0 = INV12 / l0;
            const float sc1 = INV12 / l1;
            const ushort_t* p0 = &Ps[0][arow * PSW + acg * 16];
            const ushort_t* p1 = &Ps[1][arow * PSW + acg * 16];
            #pragma unroll
            for (int k = 0; k < 4; ++k) {
                ushort4 u0 = *(const ushort4*)(p0 + k * 4);
                ushort4 u1 = *(const ushort4*)(p1 + k * 4);
                acc[k * 4 + 0] = fmaf(bf2f(u0.x), sc0, fmaf(bf2f(u1.x), sc1, acc[k * 4 + 0]));
                acc[k * 4 + 1] = fmaf(bf2f(u0.y), sc0, fmaf(bf2f(u1.y), sc1, acc[k * 4 + 1]));
                acc[k * 4 + 2] = fmaf(bf2f(u0.z), sc0, fmaf(bf2f(u1.z), sc1, acc[k * 4 + 2]));
                acc[k * 4 + 3] = fmaf(bf2f(u0.w), sc0, fmaf(bf2f(u1.w), sc1, acc[k * 4 + 3]));
            }
        }

        // ---- PV: wave computes head h, d-slice [ww*16, ww*16+16) ----
        {
            f32x4 oacc;
            #pragma unroll
            for (int r = 0; r < 4; ++r) oacc[r] = 0.f;
            const ushort_t* vrow = vhead + (size_t)(h * 64 + ww * 16 + lr) * SEQ + jbase + quad * 8;
            // branch-free batched V loads (clamped), one pin point
            bf16x8 vfa[8], vfb[8];
            #pragma unroll
            for (int ci = 0; ci < 8; ++ci) {
                const int cc2 = ci < nch ? ci : nch - 1;
                vfa[ci] = *(const bf16x8*)(vrow + cc2 * 64);
                vfb[ci] = *(const bf16x8*)(vrow + cc2 * 64 + 32);
            }
            __builtin_amdgcn_sched_barrier(0);
            #pragma unroll
            for (int ci = 0; ci < 8; ++ci) {
                if (ci < nch) {
                    const int tok0 = ci * 64;
                    bf16x8 pa0 = *(const bf16x8*)&Ps[hg][lr * PSW + tok0 + quad * 8];
                    bf16x8 pa1 = *(const bf16x8*)&Ps[hg][lr * PSW + tok0 + 32 + quad * 8];
                    oacc = __builtin_amdgcn_mfma_f32_16x16x32_bf16(pa0, vfa[ci], oacc, 0, 0, 0);
                    oacc = __builtin_amdgcn_mfma_f32_16x16x32_bf16(pa1, vfb[ci], oacc, 0, 0, 0);
                }
            }
            float lr4[4];
            #pragma unroll
            for (int r = 0; r < 4; ++r)
                lr4[r] = lsump[hg][0][quad * 4 + r] + lsump[hg][1][quad * 4 + r] +
                         lsump[hg][2][quad * 4 + r] + lsump[hg][3][quad * 4 + r];
            #pragma unroll
            for (int r = 0; r < 4; ++r) {
                const int row = iq0 + quad * 4 + r;
                values[(size_t)(b * SEQ + row) * EDIM + h * 64 + ww * 16 + lr] =
                    f2bf(oacc[r] / lr4[r]);
            }
        }
        __syncthreads();   // Ps/lsump reuse next head pair (keeps waves time-aligned)
    }

    // ---- write attn_mean ----
    if (acg * 16 < span) {
        float* dst = attn_out + ((size_t)b * SEQ + iq0 + arow) * SEQ + jbase + acg * 16;
        #pragma unroll
        for (int k = 0; k < 4; ++k) {
            float4 v = { acc[k * 4 + 0], acc[k * 4 + 1], acc[k * 4 + 2], acc[k * 4 + 3] };
            *(float4*)(dst + k * 4) = v;
        }
    }
    {
        const int c4lo = jbase >> 2;
        const int c4hi = (jbase + span) >> 2;
        const float4 z = {0.f, 0.f, 0.f, 0.f};
        for (int f = tid; f < 16 * 512; f += 512) {
            const int i  = f >> 9;
            const int c4 = f & 511;
            if (c4 < c4lo || c4 >= c4hi)
                *(float4*)(attn_out + ((size_t)b * SEQ + iq0 + i) * SEQ + c4 * 4) = z;
        }
    }
}

extern "C" void kernel_launch(void* const* d_in, const int* in_sizes, int n_in,
                              void* d_out, int out_size, void* d_ws, size_t ws_size,
                              hipStream_t stream) {
    const float* x      = (const float*)d_in[0];
    const int*   pad    = (const int*)d_in[1];
    const float* mmask  = (const float*)d_in[2];
    const float* qkv_w  = (const float*)d_in[3];
    const float* qkv_b  = (const float*)d_in[4];
    const float* o_w    = (const float*)d_in[5];
    const float* o_b    = (const float*)d_in[6];

    float* out_o    = (float*)d_out;
    float* out_attn = out_o + (size_t)NB * SEQ * EDIM;

    ushort_t* qkh    = (ushort_t*)d_ws;                       // NB*NH*SEQ*128  25.2 MB
    ushort_t* vt     = qkh + (size_t)NB * NH * SEQ * 128;     // NB*NH*64*SEQ   12.6 MB
    ushort_t* xb     = vt + (size_t)NB * NH * 64 * SEQ;       // x bf16         12.6 MB
    ushort_t* values = xb;                                    // alias (after GEMM1)
    ushort_t* wqkvb  = xb + (size_t)NB * SEQ * DIN;           // qkv_w bf16      3.5 MB
    ushort_t* wob    = wqkvb + (size_t)QKVN * DIN;            // o_w bf16        1.2 MB

    const int nx = NB * SEQ * DIN / 4, nw1 = QKVN * DIN / 4, nw2 = EDIM * EDIM / 4;
    cvt3_kernel<<<(nx + nw1 + nw2 + 255) / 256, 256, 0, stream>>>(
        x, nx, qkv_w, nw1, o_w, nw2, xb, wqkvb, wob);

    mfma_gemm128<1><<<dim3(QKVN / 128, (NB * SEQ) / 128), 256, 0, stream>>>(
        xb, wqkvb, qkv_b, nullptr, qkh, vt, QKVN, DIN);

    attn_kernel<<<512, 512, 0, stream>>>(
        qkh, vt, mmask, pad, values, out_attn);

    mfma_gemm128<0><<<dim3(EDIM / 128, (NB * SEQ) / 128), 256, 0, stream>>>(
        values, wob, o_b, out_o, nullptr, nullptr, EDIM, EDIM);
}

// Round 6
// 383.699 us; speedup vs baseline: 1.7696x; 1.1027x over previous
//
#include <hip/hip_runtime.h>

#define SEQ 2048
#define NB 4
#define DIN 768
#define EDIM 768
#define NH 12
#define QKVN 2304
#define SCALE 0.125f
#define PADV -1e9f
#define INV12 (0.0833333333f)
#define PSW 520   // Ps row stride in elems

typedef unsigned short ushort_t;
typedef __attribute__((ext_vector_type(8))) short bf16x8;
typedef __attribute__((ext_vector_type(4))) float f32x4;

__device__ __forceinline__ float bf2f(ushort_t u) {
    union { unsigned int i; float f; } v; v.i = ((unsigned int)u) << 16; return v.f;
}
__device__ __forceinline__ ushort_t f2bf(float f) {
    union { float f; unsigned int i; } v; v.f = f;
    unsigned int r = (v.i + 0x7fffu + ((v.i >> 16) & 1u)) >> 16;
    return (ushort_t)r;
}
__device__ __forceinline__ void gl_lds16(const ushort_t* g, ushort_t* l) {
    __builtin_amdgcn_global_load_lds(
        (const __attribute__((address_space(1))) unsigned int*)(g),
        (__attribute__((address_space(3))) unsigned int*)(l),
        16, 0, 0);
}

// ---------------- fp32 -> bf16 conversion, 3 regions in one launch ----------------
__global__ void cvt3_kernel(const float* __restrict__ s0, int n0,
                            const float* __restrict__ s1, int n1,
                            const float* __restrict__ s2, int n2,
                            ushort_t* __restrict__ d0, ushort_t* __restrict__ d1,
                            ushort_t* __restrict__ d2) {
    int i = blockIdx.x * blockDim.x + threadIdx.x;
    const float* src; ushort_t* dst; int off;
    if (i < n0)               { src = s0; dst = d0; off = i; }
    else if (i < n0 + n1)     { src = s1; dst = d1; off = i - n0; }
    else if (i < n0 + n1 + n2){ src = s2; dst = d2; off = i - n0 - n1; }
    else return;
    float4 f = ((const float4*)src)[off];
    ushort4 u;
    u.x = f2bf(f.x); u.y = f2bf(f.y); u.z = f2bf(f.z); u.w = f2bf(f.w);
    ((ushort4*)dst)[off] = u;
}

// ---------------- 128x128 bf16 MFMA GEMM ----------------
// MODE 0: fp32 out. MODE 1: bf16 out split into qkh[b][h][tok][128] (Q|K) and
// vt[b][h][d][tok] (transposed V).
template<int MODE>
__global__ __launch_bounds__(256) void mfma_gemm128(
    const ushort_t* __restrict__ A, const ushort_t* __restrict__ Bw,
    const float* __restrict__ bias, float* __restrict__ outf,
    ushort_t* __restrict__ qkh, ushort_t* __restrict__ vt, int N, int K)
{
    __shared__ __align__(16) ushort_t Al[128 * 64];
    __shared__ __align__(16) ushort_t Bl[128 * 64];
    const int tid  = threadIdx.x;
    const int w    = tid >> 6;
    const int l    = tid & 63;
    const int quad = l >> 4;
    const int lr   = l & 15;
    const int mw   = (w >> 1) * 64;
    const int nw   = (w & 1) * 64;
    const int bm   = blockIdx.y * 128;
    const int bn   = blockIdx.x * 128;
    const int srow = l >> 3;
    const int sg   = (l & 7) ^ srow;

    f32x4 acc[4][4];
    #pragma unroll
    for (int i = 0; i < 4; ++i)
        #pragma unroll
        for (int j = 0; j < 4; ++j)
            #pragma unroll
            for (int r = 0; r < 4; ++r) acc[i][j][r] = 0.f;

    const ushort_t* ga = A  + (size_t)(bm + w * 32 + srow) * K + sg * 8;
    const ushort_t* gb = Bw + (size_t)(bn + w * 32 + srow) * K + sg * 8;
    ushort_t* la = &Al[(w * 32) * 64];
    ushort_t* lb = &Bl[(w * 32) * 64];

    for (int k0 = 0; k0 < K; k0 += 64) {
        __syncthreads();
        #pragma unroll
        for (int i = 0; i < 4; ++i)
            gl_lds16(ga + (size_t)(i * 8) * K + k0, la + i * 8 * 64);
        #pragma unroll
        for (int i = 0; i < 4; ++i)
            gl_lds16(gb + (size_t)(i * 8) * K + k0, lb + i * 8 * 64);
        __syncthreads();
        #pragma unroll
        for (int s = 0; s < 2; ++s) {
            bf16x8 af[4], bf[4];
            #pragma unroll
            for (int t = 0; t < 4; ++t)
                af[t] = *(const bf16x8*)&Al[(mw + t * 16 + lr) * 64 + (((4 * s + quad) ^ (lr & 7)) * 8)];
            #pragma unroll
            for (int t = 0; t < 4; ++t)
                bf[t] = *(const bf16x8*)&Bl[(nw + t * 16 + lr) * 64 + (((4 * s + quad) ^ (lr & 7)) * 8)];
            #pragma unroll
            for (int mt = 0; mt < 4; ++mt)
                #pragma unroll
                for (int nt = 0; nt < 4; ++nt)
                    acc[mt][nt] = __builtin_amdgcn_mfma_f32_16x16x32_bf16(af[mt], bf[nt], acc[mt][nt], 0, 0, 0);
        }
    }

    #pragma unroll
    for (int nt = 0; nt < 4; ++nt) {
        const int gn = bn + nw + nt * 16 + lr;
        const float bv = bias[gn];
        const int hh  = gn / 192;
        const int rem = gn - hh * 192;
        #pragma unroll
        for (int mt = 0; mt < 4; ++mt) {
            const int gm0 = bm + mw + mt * 16 + quad * 4;
            if (MODE == 0) {
                #pragma unroll
                for (int r = 0; r < 4; ++r)
                    outf[(size_t)(gm0 + r) * N + gn] = acc[mt][nt][r] + bv;
            } else if (rem < 128) {
                const int bb  = gm0 >> 11;
                const int tok = gm0 & (SEQ - 1);
                #pragma unroll
                for (int r = 0; r < 4; ++r)
                    qkh[((size_t)(bb * NH + hh) * SEQ + tok + r) * 128 + rem] =
                        f2bf(acc[mt][nt][r] + bv);
            } else {
                const int bb  = gm0 >> 11;
                const int tok = gm0 & (SEQ - 1);
                ushort4 st;
                st.x = f2bf(acc[mt][nt][0] + bv);
                st.y = f2bf(acc[mt][nt][1] + bv);
                st.z = f2bf(acc[mt][nt][2] + bv);
                st.w = f2bf(acc[mt][nt][3] + bv);
                *(ushort4*)&vt[((size_t)(bb * NH + hh) * 64 + (rem - 128)) * SEQ + tok] = st;
            }
        }
    }
}

// ---------------- fused windowed attention (round-0 inner structure) ----------------
// HSPLIT=0: grid 512, each block does all 12 heads, writes attn_out directly
//           (round-0 baseline, used as fallback when workspace is small).
// HSPLIT=1: grid 1024, each block does a 6-head half (3 pair iterations) and
//           writes its attn-mean partial to ws (plain disjoint stores — round-2
//           showed global atomics RMW-amplify writes 3x). combine_kernel sums.
//           4 blocks/CU -> 32/32 waves (was 16) = 2x latency hiding.
// Round-1 lesson: keep BOTH barriers (lockstep preserves L2 locality).
// Rounds 1/3/4 lesson: per-wave load batching is impossible (compiler spills
// rather than exceed 64 VGPR) — TLP, not MLP, is the only latency lever left.
template<int HSPLIT>
__global__ __launch_bounds__(512) void attn_kernel(
    const ushort_t* __restrict__ qkh,   // [NB*NH*SEQ][128] bf16 (Q|K per head)
    const ushort_t* __restrict__ vt,    // [NB*NH*64][SEQ] bf16 (V transposed)
    const float* __restrict__ mmask,    // [NB][SEQ][SEQ]
    const int* __restrict__ pad,        // [NB][SEQ]
    ushort_t* __restrict__ values,      // [NB*SEQ][768] bf16
    float* __restrict__ attn_out,       // [NB][SEQ][SEQ]
    float* __restrict__ part)           // [2][NB][128][16][512] fp32 partials
{
    __shared__ __align__(16) ushort_t Ps[2][16 * PSW];  // 33.3 KB
    __shared__ float lsump[2][4][16];
    __shared__ int s_cnt[8];
    __shared__ int s_flags[8];
    const int tid  = threadIdx.x;
    const int w    = tid >> 6;       // 0..7
    const int hg   = w >> 2;         // head-group 0/1
    const int ww   = w & 3;          // wave within head
    const int lane = tid & 63;
    const int quad = lane >> 4;
    const int lr   = lane & 15;

    const int lin  = blockIdx.x;
    const int s    = lin & 1;
    const int b    = (lin >> 1) & 3;
    const int half = HSPLIT ? ((lin >> 3) & 1) : 0;     // head-half
    const int i16  = (HSPLIT ? (lin >> 4) : (lin >> 3)) + 64 * s;
    const int iq0  = i16 * 16;

    // ---- inline window size (popcount of valid tokens) ----
    {
        int4 pv = *(const int4*)&pad[b * SEQ + tid * 4];
        int c = (pv.x == 0) + (pv.y == 0) + (pv.z == 0) + (pv.w == 0);
        #pragma unroll
        for (int o = 32; o; o >>= 1) c += __shfl_down(c, o, 64);
        if (lane == 0) s_cnt[w] = c;
        if (tid < 8) s_flags[tid] = 0;
    }
    __syncthreads();
    int len = 0;
    #pragma unroll
    for (int k = 0; k < 8; ++k) len += s_cnt[k];
    if (len > 2048) len = 2048;
    int wsz = (int)ceilf((float)len * 10.0f / 100.0f);
    if (wsz < 2) wsz = 2;

    const int jlo  = max(0, iq0 - wsz);
    const int jhi  = min(SEQ - 1, iq0 + 15 + wsz);
    const int jt0  = jlo >> 6;
    const int nch  = (jhi >> 6) - jt0 + 1;   // <= 8
    const int jbase = jt0 << 6;
    const int span  = nch << 6;              // <= 512

    // ---- inline mmask nonzero-tile flags (coalesced scan of own window) ----
    {
        const float* tp = mmask + ((size_t)b * SEQ + iq0) * SEQ + jbase;
        const int e = tid * 2, row = e >> 6, col = e & 63;
        for (int ci = 0; ci < nch; ++ci) {
            float2 v = *(const float2*)&tp[(size_t)row * SEQ + ci * 64 + col];
            if (__any(v.x != 0.f || v.y != 0.f)) {
                if (lane == 0) atomicOr(&s_flags[ci], 1);
            }
        }
    }

    // mean-accum ownership: row = tid&15, col-group = tid>>4 (16 cols each)
    const int arow = tid & 15;
    const int acg  = tid >> 4;
    float acc[16];
    #pragma unroll
    for (int k = 0; k < 16; ++k) acc[k] = 0.f;
    __syncthreads();   // s_flags ready

    const ushort_t* vhead = vt + (size_t)b * NH * 64 * SEQ;

    const int NPAIR = HSPLIT ? 3 : (NH / 2);
    for (int hp = 0; hp < NPAIR; ++hp) {
        const int h = half * 6 + hp * 2 + hg;
        const ushort_t* hbase = qkh + (size_t)(b * NH + h) * SEQ * 128;
        const ushort_t* qbase = hbase + (size_t)(iq0 + lr) * 128;
        const bf16x8 qf0 = *(const bf16x8*)(qbase + quad * 8);
        const bf16x8 qf1 = *(const bf16x8*)(qbase + 32 + quad * 8);

        // ---- QK + exp for this wave's chunks (ci = ww, ww+4) ----
        float ls[4] = {0.f, 0.f, 0.f, 0.f};
        #pragma unroll
        for (int cc = 0; cc < 2; ++cc) {
            const int ci = ww + cc * 4;
            if (ci < nch) {
                const int jc = jbase + ci * 64;
                f32x4 s4[4];
                #pragma unroll
                for (int t = 0; t < 4; ++t) {
                    const ushort_t* kr = hbase + (size_t)(jc + t * 16 + lr) * 128 + 64;
                    bf16x8 kf0 = *(const bf16x8*)(kr + quad * 8);
                    bf16x8 kf1 = *(const bf16x8*)(kr + 32 + quad * 8);
                    #pragma unroll
                    for (int r = 0; r < 4; ++r) s4[t][r] = 0.f;
                    s4[t] = __builtin_amdgcn_mfma_f32_16x16x32_bf16(qf0, kf0, s4[t], 0, 0, 0);
                    s4[t] = __builtin_amdgcn_mfma_f32_16x16x32_bf16(qf1, kf1, s4[t], 0, 0, 0);
                }
                const int anym = s_flags[ci];
                #pragma unroll
                for (int t = 0; t < 4; ++t) {
                    const int gj = jc + t * 16 + lr;
                    #pragma unroll
                    for (int r = 0; r < 4; ++r) {
                        const int gi = iq0 + quad * 4 + r;
                        float mm = 0.f;
                        if (anym) mm = mmask[((size_t)b * SEQ + gi) * SEQ + gj];
                        const int dist = gi > gj ? gi - gj : gj - gi;
                        const float p = (dist > wsz) ? 0.f : __expf(fmaf(s4[t][r], SCALE, mm));
                        ls[r] += p;
                        Ps[hg][(quad * 4 + r) * PSW + (ci * 64 + t * 16 + lr)] = f2bf(p);
                    }
                }
            }
        }
        #pragma unroll
        for (int r = 0; r < 4; ++r) {
            #pragma unroll
            for (int m = 8; m; m >>= 1) ls[r] += __shfl_xor(ls[r], m, 16);
        }
        if (lr == 0) {
            #pragma unroll
            for (int r = 0; r < 4; ++r) lsump[hg][ww][quad * 4 + r] = ls[r];
        }
        __syncthreads();

        // ---- head-mean accumulation into registers (both heads of the pair) ----
        if (acg * 16 < span) {
            const float l0 = lsump[0][0][arow] + lsump[0][1][arow] + lsump[0][2][arow] + lsump[0][3][arow];
            const float l1 = lsump[1][0][arow] + lsump[1][1][arow] + lsump[1][2][arow] + lsump[1][3][arow];
            const float sc0 = INV12 / l0;
            const float sc1 = INV12 / l1;
            const ushort_t* p0 = &Ps[0][arow * PSW + acg * 16];
            const ushort_t* p1 = &Ps[1][arow * PSW + acg * 16];
            #pragma unroll
            for (int k = 0; k < 4; ++k) {
                ushort4 u0 = *(const ushort4*)(p0 + k * 4);
                ushort4 u1 = *(const ushort4*)(p1 + k * 4);
                acc[k * 4 + 0] = fmaf(bf2f(u0.x), sc0, fmaf(bf2f(u1.x), sc1, acc[k * 4 + 0]));
                acc[k * 4 + 1] = fmaf(bf2f(u0.y), sc0, fmaf(bf2f(u1.y), sc1, acc[k * 4 + 1]));
                acc[k * 4 + 2] = fmaf(bf2f(u0.z), sc0, fmaf(bf2f(u1.z), sc1, acc[k * 4 + 2]));
                acc[k * 4 + 3] = fmaf(bf2f(u0.w), sc0, fmaf(bf2f(u1.w), sc1, acc[k * 4 + 3]));
            }
        }

        // ---- PV: wave computes head h, d-slice [ww*16, ww*16+16) ----
        {
            f32x4 oacc;
            #pragma unroll
            for (int r = 0; r < 4; ++r) oacc[r] = 0.f;
            const ushort_t* vrow = vhead + (size_t)(h * 64 + ww * 16 + lr) * SEQ + jbase;
            for (int ci = 0; ci < nch; ++ci) {
                const int tok0 = ci * 64;
                #pragma unroll
                for (int s2 = 0; s2 < 2; ++s2) {
                    bf16x8 pa = *(const bf16x8*)&Ps[hg][lr * PSW + tok0 + s2 * 32 + quad * 8];
                    bf16x8 vf = *(const bf16x8*)(vrow + tok0 + s2 * 32 + quad * 8);
                    oacc = __builtin_amdgcn_mfma_f32_16x16x32_bf16(pa, vf, oacc, 0, 0, 0);
                }
            }
            float lr4[4];
            #pragma unroll
            for (int r = 0; r < 4; ++r)
                lr4[r] = lsump[hg][0][quad * 4 + r] + lsump[hg][1][quad * 4 + r] +
                         lsump[hg][2][quad * 4 + r] + lsump[hg][3][quad * 4 + r];
            #pragma unroll
            for (int r = 0; r < 4; ++r) {
                const int row = iq0 + quad * 4 + r;
                values[(size_t)(b * SEQ + row) * EDIM + h * 64 + ww * 16 + lr] =
                    f2bf(oacc[r] / lr4[r]);
            }
        }
        __syncthreads();   // Ps/lsump reuse next head pair (keeps waves time-aligned)
    }

    if (HSPLIT) {
        // ---- write attn-mean PARTIAL (disjoint per half, coalesced, no RMW) ----
        if (acg * 16 < span) {
            float* dst = part + ((((size_t)half * NB + b) * 128 + i16) * 16 + arow) * 512 + acg * 16;
            #pragma unroll
            for (int k = 0; k < 4; ++k) {
                float4 v = { acc[k * 4 + 0], acc[k * 4 + 1], acc[k * 4 + 2], acc[k * 4 + 3] };
                *(float4*)(dst + k * 4) = v;
            }
        }
    } else {
        // ---- write attn_mean directly ----
        if (acg * 16 < span) {
            float* dst = attn_out + ((size_t)b * SEQ + iq0 + arow) * SEQ + jbase + acg * 16;
            #pragma unroll
            for (int k = 0; k < 4; ++k) {
                float4 v = { acc[k * 4 + 0], acc[k * 4 + 1], acc[k * 4 + 2], acc[k * 4 + 3] };
                *(float4*)(dst + k * 4) = v;
            }
        }
        {
            const int c4lo = jbase >> 2;
            const int c4hi = (jbase + span) >> 2;
            const float4 z = {0.f, 0.f, 0.f, 0.f};
            for (int f = tid; f < 16 * 512; f += 512) {
                const int i  = f >> 9;
                const int c4 = f & 511;
                if (c4 < c4lo || c4 >= c4hi)
                    *(float4*)(attn_out + ((size_t)b * SEQ + iq0 + i) * SEQ + c4 * 4) = z;
            }
        }
    }
}

// ---------------- attn-mean combine: attn_out = part0 + part1 (window), 0 outside ----
__global__ __launch_bounds__(256) void combine_kernel(
    const float* __restrict__ part, const int* __restrict__ pad,
    float* __restrict__ attn_out)
{
    const int tid  = threadIdx.x;
    const int w    = tid >> 6;
    const int lane = tid & 63;
    const int blk  = blockIdx.x;       // 512 blocks: b = blk>>7, i16 = blk&127
    const int b    = blk >> 7;
    const int i16  = blk & 127;
    const int iq0  = i16 * 16;

    __shared__ int s_cnt[4];
    {
        const int4* pp = (const int4*)&pad[b * SEQ];
        int4 a = pp[tid * 2];
        int4 c = pp[tid * 2 + 1];
        int n = (a.x == 0) + (a.y == 0) + (a.z == 0) + (a.w == 0) +
                (c.x == 0) + (c.y == 0) + (c.z == 0) + (c.w == 0);
        #pragma unroll
        for (int o = 32; o; o >>= 1) n += __shfl_down(n, o, 64);
        if (lane == 0) s_cnt[w] = n;
    }
    __syncthreads();
    int len = s_cnt[0] + s_cnt[1] + s_cnt[2] + s_cnt[3];
    if (len > 2048) len = 2048;
    int wsz = (int)ceilf((float)len * 10.0f / 100.0f);
    if (wsz < 2) wsz = 2;
    const int jlo  = max(0, iq0 - wsz);
    const int jhi  = min(SEQ - 1, iq0 + 15 + wsz);
    const int jt0  = jlo >> 6;
    const int span = (((jhi >> 6) - jt0) + 1) << 6;
    const int jbase = jt0 << 6;

    const float* p0 = part + (((size_t)(0 * NB + b) * 128 + i16) * 16) * 512;
    const float* p1 = part + (((size_t)(1 * NB + b) * 128 + i16) * 16) * 512;

    for (int idx = tid; idx < 16 * 512; idx += 256) {
        const int row = idx >> 9;
        const int c4  = idx & 511;
        const int col = c4 * 4;
        float4 v = {0.f, 0.f, 0.f, 0.f};
        const int off = col - jbase;
        if (off >= 0 && off < span) {
            float4 a = *(const float4*)&p0[row * 512 + off];
            float4 c = *(const float4*)&p1[row * 512 + off];
            v.x = a.x + c.x; v.y = a.y + c.y; v.z = a.z + c.z; v.w = a.w + c.w;
        }
        *(float4*)&attn_out[((size_t)b * SEQ + iq0 + row) * SEQ + col] = v;
    }
}

extern "C" void kernel_launch(void* const* d_in, const int* in_sizes, int n_in,
                              void* d_out, int out_size, void* d_ws, size_t ws_size,
                              hipStream_t stream) {
    const float* x      = (const float*)d_in[0];
    const int*   pad    = (const int*)d_in[1];
    const float* mmask  = (const float*)d_in[2];
    const float* qkv_w  = (const float*)d_in[3];
    const float* qkv_b  = (const float*)d_in[4];
    const float* o_w    = (const float*)d_in[5];
    const float* o_b    = (const float*)d_in[6];

    float* out_o    = (float*)d_out;
    float* out_attn = out_o + (size_t)NB * SEQ * EDIM;

    ushort_t* qkh    = (ushort_t*)d_ws;                       // NB*NH*SEQ*128  25.2 MB
    ushort_t* vt     = qkh + (size_t)NB * NH * SEQ * 128;     // NB*NH*64*SEQ   12.6 MB
    ushort_t* xb     = vt + (size_t)NB * NH * 64 * SEQ;       // x bf16         12.6 MB
    ushort_t* values = xb;                                    // alias (after GEMM1)
    ushort_t* wqkvb  = xb + (size_t)NB * SEQ * DIN;           // qkv_w bf16      3.5 MB
    ushort_t* wob    = wqkvb + (size_t)QKVN * DIN;            // o_w bf16        1.2 MB
    ushort_t* wsend  = wob + (size_t)EDIM * EDIM;             // = 55,050,240 B
    float*    part   = (float*)wsend;                          // 2*NB*128*16*512*4 = 32 MB

    const size_t base_bytes = (size_t)(wsend - (ushort_t*)d_ws) * sizeof(ushort_t);
    const size_t part_bytes = (size_t)2 * NB * 128 * 16 * 512 * sizeof(float);
    const bool   split      = ws_size >= base_bytes + part_bytes;

    const int nx = NB * SEQ * DIN / 4, nw1 = QKVN * DIN / 4, nw2 = EDIM * EDIM / 4;
    cvt3_kernel<<<(nx + nw1 + nw2 + 255) / 256, 256, 0, stream>>>(
        x, nx, qkv_w, nw1, o_w, nw2, xb, wqkvb, wob);

    mfma_gemm128<1><<<dim3(QKVN / 128, (NB * SEQ) / 128), 256, 0, stream>>>(
        xb, wqkvb, qkv_b, nullptr, qkh, vt, QKVN, DIN);

    if (split) {
        attn_kernel<1><<<1024, 512, 0, stream>>>(
            qkh, vt, mmask, pad, values, out_attn, part);
        combine_kernel<<<512, 256, 0, stream>>>(part, pad, out_attn);
    } else {
        attn_kernel<0><<<512, 512, 0, stream>>>(
            qkh, vt, mmask, pad, values, out_attn, part);
    }

    mfma_gemm128<0><<<dim3(EDIM / 128, (NB * SEQ) / 128), 256, 0, stream>>>(
        values, wob, o_b, out_o, nullptr, nullptr, EDIM, EDIM);
}

// Round 7
// 378.167 us; speedup vs baseline: 1.7954x; 1.0146x over previous
//
#include <hip/hip_runtime.h>

#define SEQ 2048
#define NB 4
#define DIN 768
#define EDIM 768
#define NH 12
#define QKVN 2304
#define SCALE 0.125f
#define PADV -1e9f
#define INV12 (0.0833333333f)
#define PSW 520   // Ps row stride in elems

typedef unsigned short ushort_t;
typedef __attribute__((ext_vector_type(8))) short bf16x8;
typedef __attribute__((ext_vector_type(4))) float f32x4;

__device__ __forceinline__ float bf2f(ushort_t u) {
    union { unsigned int i; float f; } v; v.i = ((unsigned int)u) << 16; return v.f;
}
__device__ __forceinline__ ushort_t f2bf(float f) {
    union { float f; unsigned int i; } v; v.f = f;
    unsigned int r = (v.i + 0x7fffu + ((v.i >> 16) & 1u)) >> 16;
    return (ushort_t)r;
}
__device__ __forceinline__ void gl_lds16(const ushort_t* g, ushort_t* l) {
    __builtin_amdgcn_global_load_lds(
        (const __attribute__((address_space(1))) unsigned int*)(g),
        (__attribute__((address_space(3))) unsigned int*)(l),
        16, 0, 0);
}

// ---------------- fp32 -> bf16 conversion, 3 regions in one launch ----------------
__global__ void cvt3_kernel(const float* __restrict__ s0, int n0,
                            const float* __restrict__ s1, int n1,
                            const float* __restrict__ s2, int n2,
                            ushort_t* __restrict__ d0, ushort_t* __restrict__ d1,
                            ushort_t* __restrict__ d2) {
    int i = blockIdx.x * blockDim.x + threadIdx.x;
    const float* src; ushort_t* dst; int off;
    if (i < n0)               { src = s0; dst = d0; off = i; }
    else if (i < n0 + n1)     { src = s1; dst = d1; off = i - n0; }
    else if (i < n0 + n1 + n2){ src = s2; dst = d2; off = i - n0 - n1; }
    else return;
    float4 f = ((const float4*)src)[off];
    ushort4 u;
    u.x = f2bf(f.x); u.y = f2bf(f.y); u.z = f2bf(f.z); u.w = f2bf(f.w);
    ((ushort4*)dst)[off] = u;
}

// ---------------- 128x128 bf16 MFMA GEMM ----------------
// MODE 0: fp32 out. MODE 1: bf16 out split into qkh[b][h][tok][128] (Q|K) and
// vt[b][h][d][tok] (transposed V).
template<int MODE>
__global__ __launch_bounds__(256) void mfma_gemm128(
    const ushort_t* __restrict__ A, const ushort_t* __restrict__ Bw,
    const float* __restrict__ bias, float* __restrict__ outf,
    ushort_t* __restrict__ qkh, ushort_t* __restrict__ vt, int N, int K)
{
    __shared__ __align__(16) ushort_t Al[128 * 64];
    __shared__ __align__(16) ushort_t Bl[128 * 64];
    const int tid  = threadIdx.x;
    const int w    = tid >> 6;
    const int l    = tid & 63;
    const int quad = l >> 4;
    const int lr   = l & 15;
    const int mw   = (w >> 1) * 64;
    const int nw   = (w & 1) * 64;
    const int bm   = blockIdx.y * 128;
    const int bn   = blockIdx.x * 128;
    const int srow = l >> 3;
    const int sg   = (l & 7) ^ srow;

    f32x4 acc[4][4];
    #pragma unroll
    for (int i = 0; i < 4; ++i)
        #pragma unroll
        for (int j = 0; j < 4; ++j)
            #pragma unroll
            for (int r = 0; r < 4; ++r) acc[i][j][r] = 0.f;

    const ushort_t* ga = A  + (size_t)(bm + w * 32 + srow) * K + sg * 8;
    const ushort_t* gb = Bw + (size_t)(bn + w * 32 + srow) * K + sg * 8;
    ushort_t* la = &Al[(w * 32) * 64];
    ushort_t* lb = &Bl[(w * 32) * 64];

    for (int k0 = 0; k0 < K; k0 += 64) {
        __syncthreads();
        #pragma unroll
        for (int i = 0; i < 4; ++i)
            gl_lds16(ga + (size_t)(i * 8) * K + k0, la + i * 8 * 64);
        #pragma unroll
        for (int i = 0; i < 4; ++i)
            gl_lds16(gb + (size_t)(i * 8) * K + k0, lb + i * 8 * 64);
        __syncthreads();
        #pragma unroll
        for (int s = 0; s < 2; ++s) {
            bf16x8 af[4], bf[4];
            #pragma unroll
            for (int t = 0; t < 4; ++t)
                af[t] = *(const bf16x8*)&Al[(mw + t * 16 + lr) * 64 + (((4 * s + quad) ^ (lr & 7)) * 8)];
            #pragma unroll
            for (int t = 0; t < 4; ++t)
                bf[t] = *(const bf16x8*)&Bl[(nw + t * 16 + lr) * 64 + (((4 * s + quad) ^ (lr & 7)) * 8)];
            #pragma unroll
            for (int mt = 0; mt < 4; ++mt)
                #pragma unroll
                for (int nt = 0; nt < 4; ++nt)
                    acc[mt][nt] = __builtin_amdgcn_mfma_f32_16x16x32_bf16(af[mt], bf[nt], acc[mt][nt], 0, 0, 0);
        }
    }

    #pragma unroll
    for (int nt = 0; nt < 4; ++nt) {
        const int gn = bn + nw + nt * 16 + lr;
        const float bv = bias[gn];
        const int hh  = gn / 192;
        const int rem = gn - hh * 192;
        #pragma unroll
        for (int mt = 0; mt < 4; ++mt) {
            const int gm0 = bm + mw + mt * 16 + quad * 4;
            if (MODE == 0) {
                #pragma unroll
                for (int r = 0; r < 4; ++r)
                    outf[(size_t)(gm0 + r) * N + gn] = acc[mt][nt][r] + bv;
            } else if (rem < 128) {
                const int bb  = gm0 >> 11;
                const int tok = gm0 & (SEQ - 1);
                #pragma unroll
                for (int r = 0; r < 4; ++r)
                    qkh[((size_t)(bb * NH + hh) * SEQ + tok + r) * 128 + rem] =
                        f2bf(acc[mt][nt][r] + bv);
            } else {
                const int bb  = gm0 >> 11;
                const int tok = gm0 & (SEQ - 1);
                ushort4 st;
                st.x = f2bf(acc[mt][nt][0] + bv);
                st.y = f2bf(acc[mt][nt][1] + bv);
                st.z = f2bf(acc[mt][nt][2] + bv);
                st.w = f2bf(acc[mt][nt][3] + bv);
                *(ushort4*)&vt[((size_t)(bb * NH + hh) * 64 + (rem - 128)) * SEQ + tok] = st;
            }
        }
    }
}

// ---------------- fused windowed attention (round-0 inner structure) ----------------
// HSPLIT=0: grid 512, each block does all 12 heads, writes attn_out directly.
// HSPLIT=1: grid 1024, each block does a 6-head half; attn-mean partials to ws
//           (plain disjoint stores, no RMW); combine_kernel sums.
// Round-6 post-mortem: HSPLIT bookkeeping pushed VGPR to 68 -> occupancy cliff
// (waves/CU halve past 64, m69) -> 2 blocks/CU, grid serialized, SLOWER.
// Round-7 fix: __launch_bounds__(512, 8) = 8 waves/SIMD min -> hard 64-VGPR cap
// -> 4 blocks/CU genuinely co-resident (LDS 4x34.3=137<=160 KB) -> 32/32 waves.
// Round-1 lesson: keep BOTH barriers. Round-2: no global atomics.
// Rounds 1/3/4: per-wave load batching impossible (compiler spills past 64).
template<int HSPLIT>
__global__ __launch_bounds__(512, 8) void attn_kernel(
    const ushort_t* __restrict__ qkh,   // [NB*NH*SEQ][128] bf16 (Q|K per head)
    const ushort_t* __restrict__ vt,    // [NB*NH*64][SEQ] bf16 (V transposed)
    const float* __restrict__ mmask,    // [NB][SEQ][SEQ]
    const int* __restrict__ pad,        // [NB][SEQ]
    ushort_t* __restrict__ values,      // [NB*SEQ][768] bf16
    float* __restrict__ attn_out,       // [NB][SEQ][SEQ]
    float* __restrict__ part)           // [2][NB][128][16][512] fp32 partials
{
    __shared__ __align__(16) ushort_t Ps[2][16 * PSW];  // 33.3 KB
    __shared__ float lsump[2][4][16];
    __shared__ int s_cnt[8];
    __shared__ int s_flags[8];
    const int tid  = threadIdx.x;
    const int w    = tid >> 6;       // 0..7
    const int hg   = w >> 2;         // head-group 0/1
    const int ww   = w & 3;          // wave within head
    const int lane = tid & 63;
    const int quad = lane >> 4;
    const int lr   = lane & 15;

    const int lin  = blockIdx.x;
    const int s    = lin & 1;
    const int b    = (lin >> 1) & 3;
    const int half = HSPLIT ? ((lin >> 3) & 1) : 0;     // head-half
    const int i16  = (HSPLIT ? (lin >> 4) : (lin >> 3)) + 64 * s;
    const int iq0  = i16 * 16;

    // ---- inline window size (popcount of valid tokens) ----
    {
        int4 pv = *(const int4*)&pad[b * SEQ + tid * 4];
        int c = (pv.x == 0) + (pv.y == 0) + (pv.z == 0) + (pv.w == 0);
        #pragma unroll
        for (int o = 32; o; o >>= 1) c += __shfl_down(c, o, 64);
        if (lane == 0) s_cnt[w] = c;
        if (tid < 8) s_flags[tid] = 0;
    }
    __syncthreads();
    int len = 0;
    #pragma unroll
    for (int k = 0; k < 8; ++k) len += s_cnt[k];
    if (len > 2048) len = 2048;
    int wsz = (int)ceilf((float)len * 10.0f / 100.0f);
    if (wsz < 2) wsz = 2;

    const int jlo  = max(0, iq0 - wsz);
    const int jhi  = min(SEQ - 1, iq0 + 15 + wsz);
    const int jt0  = jlo >> 6;
    const int nch  = (jhi >> 6) - jt0 + 1;   // <= 8
    const int jbase = jt0 << 6;
    const int span  = nch << 6;              // <= 512

    // ---- inline mmask nonzero-tile flags (coalesced scan of own window) ----
    {
        const float* tp = mmask + ((size_t)b * SEQ + iq0) * SEQ + jbase;
        const int e = tid * 2, row = e >> 6, col = e & 63;
        for (int ci = 0; ci < nch; ++ci) {
            float2 v = *(const float2*)&tp[(size_t)row * SEQ + ci * 64 + col];
            if (__any(v.x != 0.f || v.y != 0.f)) {
                if (lane == 0) atomicOr(&s_flags[ci], 1);
            }
        }
    }

    // mean-accum ownership: row = tid&15, col-group = tid>>4 (16 cols each)
    const int arow = tid & 15;
    const int acg  = tid >> 4;
    float acc[16];
    #pragma unroll
    for (int k = 0; k < 16; ++k) acc[k] = 0.f;
    __syncthreads();   // s_flags ready

    const ushort_t* vhead = vt + (size_t)b * NH * 64 * SEQ;

    const int NPAIR = HSPLIT ? 3 : (NH / 2);
    for (int hp = 0; hp < NPAIR; ++hp) {
        const int h = half * 6 + hp * 2 + hg;
        const ushort_t* hbase = qkh + (size_t)(b * NH + h) * SEQ * 128;
        const ushort_t* qbase = hbase + (size_t)(iq0 + lr) * 128;
        const bf16x8 qf0 = *(const bf16x8*)(qbase + quad * 8);
        const bf16x8 qf1 = *(const bf16x8*)(qbase + 32 + quad * 8);

        // ---- QK + exp for this wave's chunks (ci = ww, ww+4) ----
        float ls[4] = {0.f, 0.f, 0.f, 0.f};
        #pragma unroll
        for (int cc = 0; cc < 2; ++cc) {
            const int ci = ww + cc * 4;
            if (ci < nch) {
                const int jc = jbase + ci * 64;
                f32x4 s4[4];
                #pragma unroll
                for (int t = 0; t < 4; ++t) {
                    const ushort_t* kr = hbase + (size_t)(jc + t * 16 + lr) * 128 + 64;
                    bf16x8 kf0 = *(const bf16x8*)(kr + quad * 8);
                    bf16x8 kf1 = *(const bf16x8*)(kr + 32 + quad * 8);
                    #pragma unroll
                    for (int r = 0; r < 4; ++r) s4[t][r] = 0.f;
                    s4[t] = __builtin_amdgcn_mfma_f32_16x16x32_bf16(qf0, kf0, s4[t], 0, 0, 0);
                    s4[t] = __builtin_amdgcn_mfma_f32_16x16x32_bf16(qf1, kf1, s4[t], 0, 0, 0);
                }
                const int anym = s_flags[ci];
                #pragma unroll
                for (int t = 0; t < 4; ++t) {
                    const int gj = jc + t * 16 + lr;
                    #pragma unroll
                    for (int r = 0; r < 4; ++r) {
                        const int gi = iq0 + quad * 4 + r;
                        float mm = 0.f;
                        if (anym) mm = mmask[((size_t)b * SEQ + gi) * SEQ + gj];
                        const int dist = gi > gj ? gi - gj : gj - gi;
                        const float p = (dist > wsz) ? 0.f : __expf(fmaf(s4[t][r], SCALE, mm));
                        ls[r] += p;
                        Ps[hg][(quad * 4 + r) * PSW + (ci * 64 + t * 16 + lr)] = f2bf(p);
                    }
                }
            }
        }
        #pragma unroll
        for (int r = 0; r < 4; ++r) {
            #pragma unroll
            for (int m = 8; m; m >>= 1) ls[r] += __shfl_xor(ls[r], m, 16);
        }
        if (lr == 0) {
            #pragma unroll
            for (int r = 0; r < 4; ++r) lsump[hg][ww][quad * 4 + r] = ls[r];
        }
        __syncthreads();

        // ---- head-mean accumulation into registers (both heads of the pair) ----
        if (acg * 16 < span) {
            const float l0 = lsump[0][0][arow] + lsump[0][1][arow] + lsump[0][2][arow] + lsump[0][3][arow];
            const float l1 = lsump[1][0][arow] + lsump[1][1][arow] + lsump[1][2][arow] + lsump[1][3][arow];
            const float sc0 = INV12 / l0;
            const float sc1 = INV12 / l1;
            const ushort_t* p0 = &Ps[0][arow * PSW + acg * 16];
            const ushort_t* p1 = &Ps[1][arow * PSW + acg * 16];
            #pragma unroll
            for (int k = 0; k < 4; ++k) {
                ushort4 u0 = *(const ushort4*)(p0 + k * 4);
                ushort4 u1 = *(const ushort4*)(p1 + k * 4);
                acc[k * 4 + 0] = fmaf(bf2f(u0.x), sc0, fmaf(bf2f(u1.x), sc1, acc[k * 4 + 0]));
                acc[k * 4 + 1] = fmaf(bf2f(u0.y), sc0, fmaf(bf2f(u1.y), sc1, acc[k * 4 + 1]));
                acc[k * 4 + 2] = fmaf(bf2f(u0.z), sc0, fmaf(bf2f(u1.z), sc1, acc[k * 4 + 2]));
                acc[k * 4 + 3] = fmaf(bf2f(u0.w), sc0, fmaf(bf2f(u1.w), sc1, acc[k * 4 + 3]));
            }
        }

        // ---- PV: wave computes head h, d-slice [ww*16, ww*16+16) ----
        {
            f32x4 oacc;
            #pragma unroll
            for (int r = 0; r < 4; ++r) oacc[r] = 0.f;
            const ushort_t* vrow = vhead + (size_t)(h * 64 + ww * 16 + lr) * SEQ + jbase;
            for (int ci = 0; ci < nch; ++ci) {
                const int tok0 = ci * 64;
                #pragma unroll
                for (int s2 = 0; s2 < 2; ++s2) {
                    bf16x8 pa = *(const bf16x8*)&Ps[hg][lr * PSW + tok0 + s2 * 32 + quad * 8];
                    bf16x8 vf = *(const bf16x8*)(vrow + tok0 + s2 * 32 + quad * 8);
                    oacc = __builtin_amdgcn_mfma_f32_16x16x32_bf16(pa, vf, oacc, 0, 0, 0);
                }
            }
            float lr4[4];
            #pragma unroll
            for (int r = 0; r < 4; ++r)
                lr4[r] = lsump[hg][0][quad * 4 + r] + lsump[hg][1][quad * 4 + r] +
                         lsump[hg][2][quad * 4 + r] + lsump[hg][3][quad * 4 + r];
            #pragma unroll
            for (int r = 0; r < 4; ++r) {
                const int row = iq0 + quad * 4 + r;
                values[(size_t)(b * SEQ + row) * EDIM + h * 64 + ww * 16 + lr] =
                    f2bf(oacc[r] / lr4[r]);
            }
        }
        __syncthreads();   // Ps/lsump reuse next head pair (keeps waves time-aligned)
    }

    if (HSPLIT) {
        // ---- write attn-mean PARTIAL (disjoint per half, coalesced, no RMW) ----
        if (acg * 16 < span) {
            float* dst = part + ((((size_t)half * NB + b) * 128 + i16) * 16 + arow) * 512 + acg * 16;
            #pragma unroll
            for (int k = 0; k < 4; ++k) {
                float4 v = { acc[k * 4 + 0], acc[k * 4 + 1], acc[k * 4 + 2], acc[k * 4 + 3] };
                *(float4*)(dst + k * 4) = v;
            }
        }
    } else {
        // ---- write attn_mean directly ----
        if (acg * 16 < span) {
            float* dst = attn_out + ((size_t)b * SEQ + iq0 + arow) * SEQ + jbase + acg * 16;
            #pragma unroll
            for (int k = 0; k < 4; ++k) {
                float4 v = { acc[k * 4 + 0], acc[k * 4 + 1], acc[k * 4 + 2], acc[k * 4 + 3] };
                *(float4*)(dst + k * 4) = v;
            }
        }
        {
            const int c4lo = jbase >> 2;
            const int c4hi = (jbase + span) >> 2;
            const float4 z = {0.f, 0.f, 0.f, 0.f};
            for (int f = tid; f < 16 * 512; f += 512) {
                const int i  = f >> 9;
                const int c4 = f & 511;
                if (c4 < c4lo || c4 >= c4hi)
                    *(float4*)(attn_out + ((size_t)b * SEQ + iq0 + i) * SEQ + c4 * 4) = z;
            }
        }
    }
}

// ---------------- attn-mean combine: attn_out = part0 + part1 (window), 0 outside ----
__global__ __launch_bounds__(256) void combine_kernel(
    const float* __restrict__ part, const int* __restrict__ pad,
    float* __restrict__ attn_out)
{
    const int tid  = threadIdx.x;
    const int w    = tid >> 6;
    const int lane = tid & 63;
    const int blk  = blockIdx.x;       // 512 blocks: b = blk>>7, i16 = blk&127
    const int b    = blk >> 7;
    const int i16  = blk & 127;
    const int iq0  = i16 * 16;

    __shared__ int s_cnt[4];
    {
        const int4* pp = (const int4*)&pad[b * SEQ];
        int4 a = pp[tid * 2];
        int4 c = pp[tid * 2 + 1];
        int n = (a.x == 0) + (a.y == 0) + (a.z == 0) + (a.w == 0) +
                (c.x == 0) + (c.y == 0) + (c.z == 0) + (c.w == 0);
        #pragma unroll
        for (int o = 32; o; o >>= 1) n += __shfl_down(n, o, 64);
        if (lane == 0) s_cnt[w] = n;
    }
    __syncthreads();
    int len = s_cnt[0] + s_cnt[1] + s_cnt[2] + s_cnt[3];
    if (len > 2048) len = 2048;
    int wsz = (int)ceilf((float)len * 10.0f / 100.0f);
    if (wsz < 2) wsz = 2;
    const int jlo  = max(0, iq0 - wsz);
    const int jhi  = min(SEQ - 1, iq0 + 15 + wsz);
    const int jt0  = jlo >> 6;
    const int span = (((jhi >> 6) - jt0) + 1) << 6;
    const int jbase = jt0 << 6;

    const float* p0 = part + (((size_t)(0 * NB + b) * 128 + i16) * 16) * 512;
    const float* p1 = part + (((size_t)(1 * NB + b) * 128 + i16) * 16) * 512;

    for (int idx = tid; idx < 16 * 512; idx += 256) {
        const int row = idx >> 9;
        const int c4  = idx & 511;
        const int col = c4 * 4;
        float4 v = {0.f, 0.f, 0.f, 0.f};
        const int off = col - jbase;
        if (off >= 0 && off < span) {
            float4 a = *(const float4*)&p0[row * 512 + off];
            float4 c = *(const float4*)&p1[row * 512 + off];
            v.x = a.x + c.x; v.y = a.y + c.y; v.z = a.z + c.z; v.w = a.w + c.w;
        }
        *(float4*)&attn_out[((size_t)b * SEQ + iq0 + row) * SEQ + col] = v;
    }
}

extern "C" void kernel_launch(void* const* d_in, const int* in_sizes, int n_in,
                              void* d_out, int out_size, void* d_ws, size_t ws_size,
                              hipStream_t stream) {
    const float* x      = (const float*)d_in[0];
    const int*   pad    = (const int*)d_in[1];
    const float* mmask  = (const float*)d_in[2];
    const float* qkv_w  = (const float*)d_in[3];
    const float* qkv_b  = (const float*)d_in[4];
    const float* o_w    = (const float*)d_in[5];
    const float* o_b    = (const float*)d_in[6];

    float* out_o    = (float*)d_out;
    float* out_attn = out_o + (size_t)NB * SEQ * EDIM;

    ushort_t* qkh    = (ushort_t*)d_ws;                       // NB*NH*SEQ*128  25.2 MB
    ushort_t* vt     = qkh + (size_t)NB * NH * SEQ * 128;     // NB*NH*64*SEQ   12.6 MB
    ushort_t* xb     = vt + (size_t)NB * NH * 64 * SEQ;       // x bf16         12.6 MB
    ushort_t* values = xb;                                    // alias (after GEMM1)
    ushort_t* wqkvb  = xb + (size_t)NB * SEQ * DIN;           // qkv_w bf16      3.5 MB
    ushort_t* wob    = wqkvb + (size_t)QKVN * DIN;            // o_w bf16        1.2 MB
    ushort_t* wsend  = wob + (size_t)EDIM * EDIM;             // = 55,050,240 B
    float*    part   = (float*)wsend;                          // 2*NB*128*16*512*4 = 32 MB

    const size_t base_bytes = (size_t)(wsend - (ushort_t*)d_ws) * sizeof(ushort_t);
    const size_t part_bytes = (size_t)2 * NB * 128 * 16 * 512 * sizeof(float);
    const bool   split      = ws_size >= base_bytes + part_bytes;

    const int nx = NB * SEQ * DIN / 4, nw1 = QKVN * DIN / 4, nw2 = EDIM * EDIM / 4;
    cvt3_kernel<<<(nx + nw1 + nw2 + 255) / 256, 256, 0, stream>>>(
        x, nx, qkv_w, nw1, o_w, nw2, xb, wqkvb, wob);

    mfma_gemm128<1><<<dim3(QKVN / 128, (NB * SEQ) / 128), 256, 0, stream>>>(
        xb, wqkvb, qkv_b, nullptr, qkh, vt, QKVN, DIN);

    if (split) {
        attn_kernel<1><<<1024, 512, 0, stream>>>(
            qkh, vt, mmask, pad, values, out_attn, part);
        combine_kernel<<<512, 256, 0, stream>>>(part, pad, out_attn);
    } else {
        attn_kernel<0><<<512, 512, 0, stream>>>(
            qkh, vt, mmask, pad, values, out_attn, part);
    }

    mfma_gemm128<0><<<dim3(EDIM / 128, (NB * SEQ) / 128), 256, 0, stream>>>(
        values, wob, o_b, out_o, nullptr, nullptr, EDIM, EDIM);
}

// Round 8
// 339.737 us; speedup vs baseline: 1.9985x; 1.1131x over previous
//
#include <hip/hip_runtime.h>

#define SEQ 2048
#define NB 4
#define DIN 768
#define EDIM 768
#define NH 12
#define QKVN 2304
#define SCALE 0.125f
#define PADV -1e9f
#define INV12 (0.0833333333f)
#define PSW 520   // Ps row stride in elems

typedef unsigned short ushort_t;
typedef __attribute__((ext_vector_type(8))) short bf16x8;
typedef __attribute__((ext_vector_type(4))) float f32x4;

__device__ __forceinline__ float bf2f(ushort_t u) {
    union { unsigned int i; float f; } v; v.i = ((unsigned int)u) << 16; return v.f;
}
__device__ __forceinline__ ushort_t f2bf(float f) {
    union { float f; unsigned int i; } v; v.f = f;
    unsigned int r = (v.i + 0x7fffu + ((v.i >> 16) & 1u)) >> 16;
    return (ushort_t)r;
}
__device__ __forceinline__ void gl_lds16(const ushort_t* g, ushort_t* l) {
    __builtin_amdgcn_global_load_lds(
        (const __attribute__((address_space(1))) unsigned int*)(g),
        (__attribute__((address_space(3))) unsigned int*)(l),
        16, 0, 0);
}

// ---------------- fp32 -> bf16 conversion, 3 regions in one launch ----------------
__global__ void cvt3_kernel(const float* __restrict__ s0, int n0,
                            const float* __restrict__ s1, int n1,
                            const float* __restrict__ s2, int n2,
                            ushort_t* __restrict__ d0, ushort_t* __restrict__ d1,
                            ushort_t* __restrict__ d2) {
    int i = blockIdx.x * blockDim.x + threadIdx.x;
    const float* src; ushort_t* dst; int off;
    if (i < n0)               { src = s0; dst = d0; off = i; }
    else if (i < n0 + n1)     { src = s1; dst = d1; off = i - n0; }
    else if (i < n0 + n1 + n2){ src = s2; dst = d2; off = i - n0 - n1; }
    else return;
    float4 f = ((const float4*)src)[off];
    ushort4 u;
    u.x = f2bf(f.x); u.y = f2bf(f.y); u.z = f2bf(f.z); u.w = f2bf(f.w);
    ((ushort4*)dst)[off] = u;
}

// ---------------- 128x128 bf16 MFMA GEMM ----------------
// MODE 0: fp32 out. MODE 1: bf16 out split into qkh[b][h][tok][128] (Q|K) and
// vt[b][h][d][tok] (transposed V).
template<int MODE>
__global__ __launch_bounds__(256) void mfma_gemm128(
    const ushort_t* __restrict__ A, const ushort_t* __restrict__ Bw,
    const float* __restrict__ bias, float* __restrict__ outf,
    ushort_t* __restrict__ qkh, ushort_t* __restrict__ vt, int N, int K)
{
    __shared__ __align__(16) ushort_t Al[128 * 64];
    __shared__ __align__(16) ushort_t Bl[128 * 64];
    const int tid  = threadIdx.x;
    const int w    = tid >> 6;
    const int l    = tid & 63;
    const int quad = l >> 4;
    const int lr   = l & 15;
    const int mw   = (w >> 1) * 64;
    const int nw   = (w & 1) * 64;
    const int bm   = blockIdx.y * 128;
    const int bn   = blockIdx.x * 128;
    const int srow = l >> 3;
    const int sg   = (l & 7) ^ srow;

    f32x4 acc[4][4];
    #pragma unroll
    for (int i = 0; i < 4; ++i)
        #pragma unroll
        for (int j = 0; j < 4; ++j)
            #pragma unroll
            for (int r = 0; r < 4; ++r) acc[i][j][r] = 0.f;

    const ushort_t* ga = A  + (size_t)(bm + w * 32 + srow) * K + sg * 8;
    const ushort_t* gb = Bw + (size_t)(bn + w * 32 + srow) * K + sg * 8;
    ushort_t* la = &Al[(w * 32) * 64];
    ushort_t* lb = &Bl[(w * 32) * 64];

    for (int k0 = 0; k0 < K; k0 += 64) {
        __syncthreads();
        #pragma unroll
        for (int i = 0; i < 4; ++i)
            gl_lds16(ga + (size_t)(i * 8) * K + k0, la + i * 8 * 64);
        #pragma unroll
        for (int i = 0; i < 4; ++i)
            gl_lds16(gb + (size_t)(i * 8) * K + k0, lb + i * 8 * 64);
        __syncthreads();
        #pragma unroll
        for (int s = 0; s < 2; ++s) {
            bf16x8 af[4], bf[4];
            #pragma unroll
            for (int t = 0; t < 4; ++t)
                af[t] = *(const bf16x8*)&Al[(mw + t * 16 + lr) * 64 + (((4 * s + quad) ^ (lr & 7)) * 8)];
            #pragma unroll
            for (int t = 0; t < 4; ++t)
                bf[t] = *(const bf16x8*)&Bl[(nw + t * 16 + lr) * 64 + (((4 * s + quad) ^ (lr & 7)) * 8)];
            #pragma unroll
            for (int mt = 0; mt < 4; ++mt)
                #pragma unroll
                for (int nt = 0; nt < 4; ++nt)
                    acc[mt][nt] = __builtin_amdgcn_mfma_f32_16x16x32_bf16(af[mt], bf[nt], acc[mt][nt], 0, 0, 0);
        }
    }

    #pragma unroll
    for (int nt = 0; nt < 4; ++nt) {
        const int gn = bn + nw + nt * 16 + lr;
        const float bv = bias[gn];
        const int hh  = gn / 192;
        const int rem = gn - hh * 192;
        #pragma unroll
        for (int mt = 0; mt < 4; ++mt) {
            const int gm0 = bm + mw + mt * 16 + quad * 4;
            if (MODE == 0) {
                #pragma unroll
                for (int r = 0; r < 4; ++r)
                    outf[(size_t)(gm0 + r) * N + gn] = acc[mt][nt][r] + bv;
            } else if (rem < 128) {
                const int bb  = gm0 >> 11;
                const int tok = gm0 & (SEQ - 1);
                #pragma unroll
                for (int r = 0; r < 4; ++r)
                    qkh[((size_t)(bb * NH + hh) * SEQ + tok + r) * 128 + rem] =
                        f2bf(acc[mt][nt][r] + bv);
            } else {
                const int bb  = gm0 >> 11;
                const int tok = gm0 & (SEQ - 1);
                ushort4 st;
                st.x = f2bf(acc[mt][nt][0] + bv);
                st.y = f2bf(acc[mt][nt][1] + bv);
                st.z = f2bf(acc[mt][nt][2] + bv);
                st.w = f2bf(acc[mt][nt][3] + bv);
                *(ushort4*)&vt[((size_t)(bb * NH + hh) * 64 + (rem - 128)) * SEQ + tok] = st;
            }
        }
    }
}

// ---------------- fused windowed attention: 32-row Q-tiles, 16 waves ----------------
// Round-8: double the Q-tile (32 rows/block), grid 256 x 1024 thr = 16 waves/CU
// (same wave count as round-0's 2x8). Each wave owns ONE chunk in QK and serves
// TWO 16-row groups from the same K fragments -> K loads per q-row HALVE.
// 1 block/CU, 4 waves/SIMD -> VGPR cap 128: the 8-fragment K batch finally fits
// in registers (rounds 3/4 failed at the 64-reg wall). Lockstep 2-barrier
// structure preserved (round-1 lesson); no atomics (round-2); no splits (r6/r7).
__global__ __launch_bounds__(1024, 4) void attn_kernel(
    const ushort_t* __restrict__ qkh,   // [NB*NH*SEQ][128] bf16 (Q|K per head)
    const ushort_t* __restrict__ vt,    // [NB*NH*64][SEQ] bf16 (V transposed)
    const float* __restrict__ mmask,    // [NB][SEQ][SEQ]
    const int* __restrict__ pad,        // [NB][SEQ]
    ushort_t* __restrict__ values,      // [NB*SEQ][768] bf16
    float* __restrict__ attn_out)       // [NB][SEQ][SEQ]
{
    __shared__ __align__(16) ushort_t Ps[2][32 * PSW];  // 66.6 KB
    __shared__ float lsump[2][8][32];                    // per-chunk row sums
    __shared__ int s_cnt[8];
    __shared__ int s_flags[8];
    const int tid  = threadIdx.x;
    const int w    = tid >> 6;       // 0..15
    const int hg   = w >> 3;         // head-group 0/1
    const int ww   = w & 7;          // wave within head-group: chunk id / PV slice
    const int lane = tid & 63;
    const int quad = lane >> 4;
    const int lr   = lane & 15;

    const int lin  = blockIdx.x;     // 256 blocks
    const int s    = lin & 1;
    const int b    = (lin >> 1) & 3;
    const int i32  = (lin >> 3) + 32 * s;    // 0..63, 32-row tile index
    const int iq0  = i32 * 32;

    // ---- inline window size (popcount of valid tokens; first 8 waves) ----
    if (tid < 512) {
        int4 pv = *(const int4*)&pad[b * SEQ + tid * 4];
        int c = (pv.x == 0) + (pv.y == 0) + (pv.z == 0) + (pv.w == 0);
        #pragma unroll
        for (int o = 32; o; o >>= 1) c += __shfl_down(c, o, 64);
        if (lane == 0) s_cnt[w] = c;
    }
    if (tid < 8) s_flags[tid] = 0;
    __syncthreads();
    int len = 0;
    #pragma unroll
    for (int k = 0; k < 8; ++k) len += s_cnt[k];
    if (len > 2048) len = 2048;
    int wsz = (int)ceilf((float)len * 10.0f / 100.0f);
    if (wsz < 2) wsz = 2;

    const int jlo  = max(0, iq0 - wsz);
    const int jhi  = min(SEQ - 1, iq0 + 31 + wsz);
    const int jt0  = jlo >> 6;
    const int nch  = (jhi >> 6) - jt0 + 1;   // <= 8 (2*205+32 = 442 span max)
    const int jbase = jt0 << 6;
    const int span  = nch << 6;              // <= 512

    // ---- inline mmask nonzero-tile flags (1024 thr x 2 = 32 rows x 64 cols) ----
    {
        const float* tp = mmask + ((size_t)b * SEQ + iq0) * SEQ + jbase;
        const int e = tid * 2, row = e >> 6, col = e & 63;
        for (int ci = 0; ci < nch; ++ci) {
            float2 v = *(const float2*)&tp[(size_t)row * SEQ + ci * 64 + col];
            if (__any(v.x != 0.f || v.y != 0.f)) {
                if (lane == 0) atomicOr(&s_flags[ci], 1);
            }
        }
    }

    // mean-accum ownership: row = tid&31, col-group = tid>>5 (16 cols each)
    const int arow = tid & 31;
    const int acg  = tid >> 5;       // 0..31
    float acc[16];
    #pragma unroll
    for (int k = 0; k < 16; ++k) acc[k] = 0.f;
    __syncthreads();   // s_flags + s_cnt consumed

    const ushort_t* vhead = vt + (size_t)b * NH * 64 * SEQ;

    for (int hp = 0; hp < NH / 2; ++hp) {
        const int h = hp * 2 + hg;
        const ushort_t* hbase = qkh + (size_t)(b * NH + h) * SEQ * 128;

        // ---- Q fragments for both 16-row groups ----
        bf16x8 qf[2][2];
        #pragma unroll
        for (int rg = 0; rg < 2; ++rg) {
            const ushort_t* qb = hbase + (size_t)(iq0 + rg * 16 + lr) * 128 + quad * 8;
            qf[rg][0] = *(const bf16x8*)(qb);
            qf[rg][1] = *(const bf16x8*)(qb + 32);
        }

        // ---- QK + exp: this wave's single chunk (ci = ww), both row groups ----
        float ls[2][4] = {{0.f,0.f,0.f,0.f},{0.f,0.f,0.f,0.f}};
        const int ci = ww;
        if (ci < nch) {
            const int jc = jbase + ci * 64;
            bf16x8 kf0[4], kf1[4];
            #pragma unroll
            for (int t = 0; t < 4; ++t) {
                const ushort_t* kr = hbase + (size_t)(jc + t * 16 + lr) * 128 + 64 + quad * 8;
                kf0[t] = *(const bf16x8*)(kr);
                kf1[t] = *(const bf16x8*)(kr + 32);
            }
            const int anym = s_flags[ci];
            #pragma unroll
            for (int rg = 0; rg < 2; ++rg) {
                f32x4 s4[4];
                #pragma unroll
                for (int t = 0; t < 4; ++t) {
                    #pragma unroll
                    for (int r = 0; r < 4; ++r) s4[t][r] = 0.f;
                    s4[t] = __builtin_amdgcn_mfma_f32_16x16x32_bf16(qf[rg][0], kf0[t], s4[t], 0, 0, 0);
                    s4[t] = __builtin_amdgcn_mfma_f32_16x16x32_bf16(qf[rg][1], kf1[t], s4[t], 0, 0, 0);
                }
                #pragma unroll
                for (int t = 0; t < 4; ++t) {
                    const int gj = jc + t * 16 + lr;
                    #pragma unroll
                    for (int r = 0; r < 4; ++r) {
                        const int gi = iq0 + rg * 16 + quad * 4 + r;
                        float mm = 0.f;
                        if (anym) mm = mmask[((size_t)b * SEQ + gi) * SEQ + gj];
                        const int dist = gi > gj ? gi - gj : gj - gi;
                        const float p = (dist > wsz) ? 0.f : __expf(fmaf(s4[t][r], SCALE, mm));
                        ls[rg][r] += p;
                        Ps[hg][(rg * 16 + quad * 4 + r) * PSW + (ci * 64 + t * 16 + lr)] = f2bf(p);
                    }
                }
            }
        }
        #pragma unroll
        for (int rg = 0; rg < 2; ++rg)
            #pragma unroll
            for (int r = 0; r < 4; ++r) {
                #pragma unroll
                for (int m = 8; m; m >>= 1) ls[rg][r] += __shfl_xor(ls[rg][r], m, 16);
            }
        if (lr == 0) {
            #pragma unroll
            for (int rg = 0; rg < 2; ++rg)
                #pragma unroll
                for (int r = 0; r < 4; ++r)
                    lsump[hg][ww][rg * 16 + quad * 4 + r] = ls[rg][r];
        }
        __syncthreads();

        // ---- head-mean accumulation into registers (both heads of the pair) ----
        if (acg * 16 < span) {
            float l0 = 0.f, l1 = 0.f;
            #pragma unroll
            for (int k = 0; k < 8; ++k) { l0 += lsump[0][k][arow]; l1 += lsump[1][k][arow]; }
            const float sc0 = INV12 / l0;
            const float sc1 = INV12 / l1;
            const ushort_t* p0 = &Ps[0][arow * PSW + acg * 16];
            const ushort_t* p1 = &Ps[1][arow * PSW + acg * 16];
            #pragma unroll
            for (int k = 0; k < 4; ++k) {
                ushort4 u0 = *(const ushort4*)(p0 + k * 4);
                ushort4 u1 = *(const ushort4*)(p1 + k * 4);
                acc[k * 4 + 0] = fmaf(bf2f(u0.x), sc0, fmaf(bf2f(u1.x), sc1, acc[k * 4 + 0]));
                acc[k * 4 + 1] = fmaf(bf2f(u0.y), sc0, fmaf(bf2f(u1.y), sc1, acc[k * 4 + 1]));
                acc[k * 4 + 2] = fmaf(bf2f(u0.z), sc0, fmaf(bf2f(u1.z), sc1, acc[k * 4 + 2]));
                acc[k * 4 + 3] = fmaf(bf2f(u0.w), sc0, fmaf(bf2f(u1.w), sc1, acc[k * 4 + 3]));
            }
        }

        // ---- PV: wave = (row-half rh, d-slice dq) of head h ----
        {
            const int rh = ww & 1;          // 16-row half
            const int dq = ww >> 1;         // d-slice 0..3 (16 cols)
            f32x4 oacc;
            #pragma unroll
            for (int r = 0; r < 4; ++r) oacc[r] = 0.f;
            const ushort_t* vrow = vhead + (size_t)(h * 64 + dq * 16 + lr) * SEQ + jbase;
            for (int ci2 = 0; ci2 < nch; ++ci2) {
                const int tok0 = ci2 * 64;
                #pragma unroll
                for (int s2 = 0; s2 < 2; ++s2) {
                    bf16x8 pa = *(const bf16x8*)&Ps[hg][(rh * 16 + lr) * PSW + tok0 + s2 * 32 + quad * 8];
                    bf16x8 vf = *(const bf16x8*)(vrow + tok0 + s2 * 32 + quad * 8);
                    oacc = __builtin_amdgcn_mfma_f32_16x16x32_bf16(pa, vf, oacc, 0, 0, 0);
                }
            }
            float lr4[4];
            #pragma unroll
            for (int r = 0; r < 4; ++r) {
                float l = 0.f;
                #pragma unroll
                for (int k = 0; k < 8; ++k) l += lsump[hg][k][rh * 16 + quad * 4 + r];
                lr4[r] = l;
            }
            #pragma unroll
            for (int r = 0; r < 4; ++r) {
                const int row = iq0 + rh * 16 + quad * 4 + r;
                values[(size_t)(b * SEQ + row) * EDIM + h * 64 + dq * 16 + lr] =
                    f2bf(oacc[r] / lr4[r]);
            }
        }
        __syncthreads();   // Ps/lsump reuse next head pair (keeps waves time-aligned)
    }

    // ---- write attn_mean ----
    if (acg * 16 < span) {
        float* dst = attn_out + ((size_t)b * SEQ + iq0 + arow) * SEQ + jbase + acg * 16;
        #pragma unroll
        for (int k = 0; k < 4; ++k) {
            float4 v = { acc[k * 4 + 0], acc[k * 4 + 1], acc[k * 4 + 2], acc[k * 4 + 3] };
            *(float4*)(dst + k * 4) = v;
        }
    }
    {
        const int c4lo = jbase >> 2;
        const int c4hi = (jbase + span) >> 2;
        const float4 z = {0.f, 0.f, 0.f, 0.f};
        for (int f = tid; f < 32 * 512; f += 1024) {
            const int i  = f >> 9;
            const int c4 = f & 511;
            if (c4 < c4lo || c4 >= c4hi)
                *(float4*)(attn_out + ((size_t)b * SEQ + iq0 + i) * SEQ + c4 * 4) = z;
        }
    }
}

extern "C" void kernel_launch(void* const* d_in, const int* in_sizes, int n_in,
                              void* d_out, int out_size, void* d_ws, size_t ws_size,
                              hipStream_t stream) {
    const float* x      = (const float*)d_in[0];
    const int*   pad    = (const int*)d_in[1];
    const float* mmask  = (const float*)d_in[2];
    const float* qkv_w  = (const float*)d_in[3];
    const float* qkv_b  = (const float*)d_in[4];
    const float* o_w    = (const float*)d_in[5];
    const float* o_b    = (const float*)d_in[6];

    float* out_o    = (float*)d_out;
    float* out_attn = out_o + (size_t)NB * SEQ * EDIM;

    ushort_t* qkh    = (ushort_t*)d_ws;                       // NB*NH*SEQ*128  25.2 MB
    ushort_t* vt     = qkh + (size_t)NB * NH * SEQ * 128;     // NB*NH*64*SEQ   12.6 MB
    ushort_t* xb     = vt + (size_t)NB * NH * 64 * SEQ;       // x bf16         12.6 MB
    ushort_t* values = xb;                                    // alias (after GEMM1)
    ushort_t* wqkvb  = xb + (size_t)NB * SEQ * DIN;           // qkv_w bf16      3.5 MB
    ushort_t* wob    = wqkvb + (size_t)QKVN * DIN;            // o_w bf16        1.2 MB

    const int nx = NB * SEQ * DIN / 4, nw1 = QKVN * DIN / 4, nw2 = EDIM * EDIM / 4;
    cvt3_kernel<<<(nx + nw1 + nw2 + 255) / 256, 256, 0, stream>>>(
        x, nx, qkv_w, nw1, o_w, nw2, xb, wqkvb, wob);

    mfma_gemm128<1><<<dim3(QKVN / 128, (NB * SEQ) / 128), 256, 0, stream>>>(
        xb, wqkvb, qkv_b, nullptr, qkh, vt, QKVN, DIN);

    attn_kernel<<<256, 1024, 0, stream>>>(
        qkh, vt, mmask, pad, values, out_attn);

    mfma_gemm128<0><<<dim3(EDIM / 128, (NB * SEQ) / 128), 256, 0, stream>>>(
        values, wob, o_b, out_o, nullptr, nullptr, EDIM, EDIM);
}